// Round 1
// baseline (19212.952 us; speedup 1.0000x reference)
//
#include <hip/hip_runtime.h>
#include <cmath>

#define NN 100000
#define NE 1600000
#define NG 512
#define H 200
#define D 205
#define EPSV 1e-5f

static __device__ __forceinline__ float sigm(float x){ return 1.0f/(1.0f+expf(-x)); }

// ---------------- transpose: out[c][r] = in[r][c], in is R x C ----------------
__global__ void ktrans(const float* __restrict__ in, float* __restrict__ out, int R, int C){
  int i = blockIdx.x*256 + threadIdx.x;
  if (i < R*C){ int r = i / C, c = i - r*C; out[c*R + r] = in[i]; }
}

// ---------------- generic tiled fp32 GEMM: C = A[MxK] @ B[KxN] ----------------
// EPIL==1: += bias, then BN(scale/shift) + ReLU.  EPIL==0: raw.
template<int EPIL>
__global__ __launch_bounds__(256) void gemm_k(
    const float* __restrict__ A, const float* __restrict__ B,
    const float* __restrict__ bias,
    const float* __restrict__ bng, const float* __restrict__ bnb,
    const float* __restrict__ bnm, const float* __restrict__ bnv,
    float* __restrict__ C, int M, int N, int K)
{
  __shared__ float As[32][68];   // [k][m], stride 68 keeps float4 16B-aligned
  __shared__ float Bs[32][68];   // [k][n]
  int tid = threadIdx.x;
  int m0 = blockIdx.x * 64, n0 = blockIdx.y * 64;
  int tx = tid & 15, ty = tid >> 4;
  float acc[4][4] = {};

  for (int k0 = 0; k0 < K; k0 += 32) {
    // A tile: 64 rows x 32 k
    #pragma unroll
    for (int p = 0; p < 2; ++p) {
      int row = (tid >> 3) + p*32;
      int kq  = (tid & 7) * 4;
      int gmr = m0 + row, gk = k0 + kq;
      float4 v = make_float4(0.f,0.f,0.f,0.f);
      if (gmr < M) {
        if (gk + 3 < K) v = *(const float4*)&A[gmr*K + gk];
        else {
          float* pv = (float*)&v;
          for (int q = 0; q < 4; ++q) if (gk + q < K) pv[q] = A[gmr*K + gk + q];
        }
      }
      As[kq+0][row]=v.x; As[kq+1][row]=v.y; As[kq+2][row]=v.z; As[kq+3][row]=v.w;
    }
    // B tile: 32 k x 64 n
    #pragma unroll
    for (int p = 0; p < 8; ++p) {
      int row = (tid >> 6) + p*4;
      int col = tid & 63;
      int gk = k0 + row, gn = n0 + col;
      float v = 0.f;
      if (gk < K && gn < N) v = B[gk*N + gn];
      Bs[row][col] = v;
    }
    __syncthreads();
    #pragma unroll
    for (int kk = 0; kk < 32; ++kk) {
      float4 a = *(const float4*)&As[kk][ty*4];
      float4 b = *(const float4*)&Bs[kk][tx*4];
      acc[0][0] += a.x*b.x; acc[0][1] += a.x*b.y; acc[0][2] += a.x*b.z; acc[0][3] += a.x*b.w;
      acc[1][0] += a.y*b.x; acc[1][1] += a.y*b.y; acc[1][2] += a.y*b.z; acc[1][3] += a.y*b.w;
      acc[2][0] += a.z*b.x; acc[2][1] += a.z*b.y; acc[2][2] += a.z*b.z; acc[2][3] += a.z*b.w;
      acc[3][0] += a.w*b.x; acc[3][1] += a.w*b.y; acc[3][2] += a.w*b.z; acc[3][3] += a.w*b.w;
    }
    __syncthreads();
  }
  #pragma unroll
  for (int i = 0; i < 4; ++i) {
    int gmr = m0 + ty*4 + i;
    if (gmr >= M) continue;
    #pragma unroll
    for (int j = 0; j < 4; ++j) {
      int gn = n0 + tx*4 + j;
      if (gn >= N) continue;
      float c = acc[i][j];
      if (EPIL == 1) {
        c += bias[gn];
        float s = bng[gn] * rsqrtf(bnv[gn] + EPSV);
        c = (c - bnm[gn]) * s + bnb[gn];
        c = fmaxf(c, 0.f);
      }
      C[gmr*N + gn] = c;
    }
  }
}

// ---------------- scatter-add over edges: agg[dst] += m[src] ----------------
__global__ __launch_bounds__(256) void scatter_k(
    const float* __restrict__ m, const int* __restrict__ src,
    const int* __restrict__ dst, float* __restrict__ agg)
{
  long tid = (long)blockIdx.x*256 + threadIdx.x;
  if (tid >= (long)NE*50) return;
  int e = (int)(tid / 50);
  int c = (int)(tid - (long)e*50);
  int s = src[e], d = dst[e];
  float4 v = ((const float4*)(m + (size_t)s*H))[c];
  float* o = agg + (size_t)d*H + c*4;
  unsafeAtomicAdd(o+0, v.x);
  unsafeAtomicAdd(o+1, v.y);
  unsafeAtomicAdd(o+2, v.z);
  unsafeAtomicAdd(o+3, v.w);
}

// ---------------- fused GRU cell: h' = GRU(agg, h) ----------------
// block: 256 thr = 64 j-lanes x 4 node-groups; 32 nodes/block, 8 nodes/thread.
__global__ __launch_bounds__(256) void gru_k(
    const float* __restrict__ agg, const float* __restrict__ h,
    const float* __restrict__ wihT, const float* __restrict__ whhT,  // [200][600]
    const float* __restrict__ bih, const float* __restrict__ bhh,
    float* __restrict__ hout)
{
  __shared__ float a_lds[32][H];
  __shared__ float h_lds[32][H];
  int tid = threadIdx.x;
  int n0 = blockIdx.x * 32;
  for (int idx = tid; idx < 32*H; idx += 256) {
    int r = idx / H, c = idx - r*H;
    a_lds[r][c] = agg[(size_t)(n0 + r)*H + c];
    h_lds[r][c] = h  [(size_t)(n0 + r)*H + c];
  }
  __syncthreads();
  int tj = tid & 63, tn = tid >> 6;
  int j = blockIdx.y * 64 + tj;
  int jc = (j < H) ? j : 0;
  float aIR[8]={},aIZ[8]={},aIN[8]={},aHR[8]={},aHZ[8]={},aHN[8]={};
  for (int k = 0; k < H; k += 2) {
    float wi0a = wihT[(k  )*600 +       jc], wi1a = wihT[(k  )*600 + 200 + jc], wi2a = wihT[(k  )*600 + 400 + jc];
    float wi0b = wihT[(k+1)*600 +       jc], wi1b = wihT[(k+1)*600 + 200 + jc], wi2b = wihT[(k+1)*600 + 400 + jc];
    float wh0a = whhT[(k  )*600 +       jc], wh1a = whhT[(k  )*600 + 200 + jc], wh2a = whhT[(k  )*600 + 400 + jc];
    float wh0b = whhT[(k+1)*600 +       jc], wh1b = whhT[(k+1)*600 + 200 + jc], wh2b = whhT[(k+1)*600 + 400 + jc];
    #pragma unroll
    for (int r = 0; r < 8; ++r) {
      float2 a  = *(const float2*)&a_lds[tn*8 + r][k];
      float2 hh = *(const float2*)&h_lds[tn*8 + r][k];
      aIR[r] += a.x*wi0a + a.y*wi0b;
      aIZ[r] += a.x*wi1a + a.y*wi1b;
      aIN[r] += a.x*wi2a + a.y*wi2b;
      aHR[r] += hh.x*wh0a + hh.y*wh0b;
      aHZ[r] += hh.x*wh1a + hh.y*wh1b;
      aHN[r] += hh.x*wh2a + hh.y*wh2b;
    }
  }
  if (j < H) {
    float bir = bih[j], biz = bih[200+j], bin = bih[400+j];
    float bhr = bhh[j], bhz = bhh[200+j], bhn = bhh[400+j];
    #pragma unroll
    for (int r = 0; r < 8; ++r) {
      int node = n0 + tn*8 + r;
      float rg = sigm(aIR[r] + bir + aHR[r] + bhr);
      float zg = sigm(aIZ[r] + biz + aHZ[r] + bhz);
      float ng = tanhf(aIN[r] + bin + rg*(aHN[r] + bhn));
      float ho = h_lds[tn*8 + r][j];
      hout[(size_t)node*H + j] = (1.f - zg)*ng + zg*ho;
    }
  }
}

// ---------------- pooling: bn2+relu then per-graph sum & max ----------------
__global__ __launch_bounds__(256) void pool_k(
    const float* __restrict__ h, const int* __restrict__ batch,
    const float* __restrict__ g2, const float* __restrict__ b2,
    const float* __restrict__ m2, const float* __restrict__ v2,
    float* __restrict__ gsum, float* __restrict__ gmax)
{
  long tid = (long)blockIdx.x*256 + threadIdx.x;
  if (tid >= (long)NN*H) return;
  int n = (int)(tid / H), j = (int)(tid - (long)n*H);
  float s = g2[j] * rsqrtf(v2[j] + EPSV);
  float val = (h[tid] - m2[j]) * s + b2[j];
  val = fmaxf(val, 0.f);
  int b = batch[n];
  unsafeAtomicAdd(&gsum[b*H + j], val);
  atomicMax((int*)&gmax[b*H + j], __float_as_int(val));  // val >= 0 -> int order ok
}

// ---------------- per-graph node counts (batch is sorted) ----------------
__global__ void cnt_k(const int* __restrict__ batch, float* __restrict__ cnt){
  int g = blockIdx.x*64 + threadIdx.x;
  if (g >= NG) return;
  int lo = 0, hi = NN;
  while (lo < hi){ int mid = (lo+hi)>>1; if (batch[mid] < g) lo = mid+1; else hi = mid; }
  int lo2 = lo, hi2 = NN;
  while (lo2 < hi2){ int mid = (lo2+hi2)>>1; if (batch[mid] < g+1) lo2 = mid+1; else hi2 = mid; }
  cnt[g] = (float)(lo2 - lo);
}

// ---------------- fc1 + bnf + relu ----------------
__global__ __launch_bounds__(256) void fc1_k(
    const float* __restrict__ gsum, const float* __restrict__ gmax,
    const float* __restrict__ cnt, const float* __restrict__ W,  // [200][400]
    const float* __restrict__ bias,
    const float* __restrict__ fg, const float* __restrict__ fb,
    const float* __restrict__ fm, const float* __restrict__ fv,
    float* __restrict__ out)
{
  int tid = blockIdx.x*256 + threadIdx.x;
  if (tid >= NG*H) return;
  int g = tid / H, j = tid - g*H;
  float inv = 1.f / fmaxf(cnt[g], 1.f);
  const float* wr = W + j*2*H;
  float acc = bias[j];
  for (int k = 0; k < H; ++k) acc += gsum[g*H + k]*inv * wr[k];
  for (int k = 0; k < H; ++k) acc += gmax[g*H + k] * wr[H + k];
  float s = fg[j] * rsqrtf(fv[j] + EPSV);
  acc = (acc - fm[j]) * s + fb[j];
  out[tid] = fmaxf(acc, 0.f);
}

// ---------------- fc2 ----------------
__global__ void fc2_k(const float* __restrict__ in, const float* __restrict__ W,
                      const float* __restrict__ bias, float* __restrict__ out)
{
  int tid = blockIdx.x*256 + threadIdx.x;
  if (tid >= NG*2) return;
  int g = tid >> 1, c = tid & 1;
  float acc = bias[c];
  const float* wr = W + c*H;
  const float* xr = in + g*H;
  for (int k = 0; k < H; ++k) acc += xr[k]*wr[k];
  out[tid] = acc;
}

extern "C" void kernel_launch(void* const* d_in, const int* in_sizes, int n_in,
                              void* d_out, int out_size, void* d_ws, size_t ws_size,
                              hipStream_t stream)
{
  const float* x     = (const float*)d_in[0];
  const int*   eidx  = (const int*)d_in[1];
  const int*   batch = (const int*)d_in[2];
  const float* projW = (const float*)d_in[3];
  const float* projb = (const float*)d_in[4];
  const float* bn1g  = (const float*)d_in[5];
  const float* bn1b  = (const float*)d_in[6];
  const float* bn1m  = (const float*)d_in[7];
  const float* bn1v  = (const float*)d_in[8];
  const float* bn2g  = (const float*)d_in[9];
  const float* bn2b  = (const float*)d_in[10];
  const float* bn2m  = (const float*)d_in[11];
  const float* bn2v  = (const float*)d_in[12];
  const float* bnfg  = (const float*)d_in[13];
  const float* bnfb  = (const float*)d_in[14];
  const float* bnfm  = (const float*)d_in[15];
  const float* bnfv  = (const float*)d_in[16];
  const float* ggcW  = (const float*)d_in[17];
  const float* wih   = (const float*)d_in[18];
  const float* whh   = (const float*)d_in[19];
  const float* bih   = (const float*)d_in[20];
  const float* bhh   = (const float*)d_in[21];
  const float* fc1W  = (const float*)d_in[22];
  const float* fc1b  = (const float*)d_in[23];
  const float* fc2W  = (const float*)d_in[24];
  const float* fc2b  = (const float*)d_in[25];

  char* wsp = (char*)d_ws;
  auto alloc = [&](size_t nfloats) {
    float* p = (float*)wsp;
    wsp += ((nfloats*sizeof(float) + 255) / 256) * 256;
    return p;
  };
  float* buf0  = alloc((size_t)NN*H);
  float* buf1  = alloc((size_t)NN*H);
  float* agg   = alloc((size_t)NN*H);
  float* projT = alloc((size_t)D*H);
  float* wihT  = alloc((size_t)H*3*H);
  float* whhT  = alloc((size_t)H*3*H);
  float* gsum  = alloc((size_t)NG*H);
  float* gmax  = alloc((size_t)NG*H);
  float* cnt   = alloc(NG);
  float* fc1o  = alloc((size_t)NG*H);

  ktrans<<<(H*D + 255)/256, 256, 0, stream>>>(projW, projT, H, D);
  ktrans<<<(3*H*H + 255)/256, 256, 0, stream>>>(wih, wihT, 3*H, H);
  ktrans<<<(3*H*H + 255)/256, 256, 0, stream>>>(whh, whhT, 3*H, H);

  dim3 gproj((NN + 63)/64, (H + 63)/64);
  gemm_k<1><<<gproj, 256, 0, stream>>>(x, projT, projb, bn1g, bn1b, bn1m, bn1v,
                                       buf0, NN, H, D);

  const int* srcp = eidx;
  const int* dstp = eidx + NE;
  float* hcur = buf0; float* hoth = buf1;
  for (int i = 0; i < 3; ++i) {
    gemm_k<0><<<gproj, 256, 0, stream>>>(hcur, ggcW + (size_t)i*H*H,
                                         nullptr, nullptr, nullptr, nullptr, nullptr,
                                         hoth, NN, H, H);
    hipMemsetAsync(agg, 0, (size_t)NN*H*sizeof(float), stream);
    scatter_k<<<(int)(((long)NE*50 + 255)/256), 256, 0, stream>>>(hoth, srcp, dstp, agg);
    gru_k<<<dim3(NN/32, 4), 256, 0, stream>>>(agg, hcur, wihT, whhT, bih, bhh, hoth);
    float* t = hcur; hcur = hoth; hoth = t;
  }

  hipMemsetAsync(gsum, 0, (size_t)NG*H*sizeof(float), stream);
  hipMemsetAsync(gmax, 0, (size_t)NG*H*sizeof(float), stream);
  pool_k<<<(int)(((long)NN*H + 255)/256), 256, 0, stream>>>(hcur, batch,
                                                            bn2g, bn2b, bn2m, bn2v,
                                                            gsum, gmax);
  cnt_k<<<(NG + 63)/64, 64, 0, stream>>>(batch, cnt);
  fc1_k<<<(NG*H + 255)/256, 256, 0, stream>>>(gsum, gmax, cnt, fc1W, fc1b,
                                              bnfg, bnfb, bnfm, bnfv, fc1o);
  fc2_k<<<(NG*2 + 255)/256, 256, 0, stream>>>(fc1o, fc2W, fc2b, (float*)d_out);
}

// Round 2
// 6218.393 us; speedup vs baseline: 3.0897x; 3.0897x over previous
//
#include <hip/hip_runtime.h>
#include <cmath>

#define NN 100000
#define NE 1600000
#define NG 512
#define H 200
#define D 205
#define EPSV 1e-5f
#define SCAN_B 1024

static __device__ __forceinline__ float sigm(float x){ return 1.0f/(1.0f+expf(-x)); }

// ---------------- transpose: out[c][r] = in[r][c], in is R x C ----------------
__global__ void ktrans(const float* __restrict__ in, float* __restrict__ out, int R, int C){
  int i = blockIdx.x*256 + threadIdx.x;
  if (i < R*C){ int r = i / C, c = i - r*C; out[c*R + r] = in[i]; }
}

// ---------------- generic tiled fp32 GEMM: C = A[MxK] @ B[KxN] ----------------
template<int EPIL>
__global__ __launch_bounds__(256) void gemm_k(
    const float* __restrict__ A, const float* __restrict__ B,
    const float* __restrict__ bias,
    const float* __restrict__ bng, const float* __restrict__ bnb,
    const float* __restrict__ bnm, const float* __restrict__ bnv,
    float* __restrict__ C, int M, int N, int K)
{
  __shared__ float As[32][68];
  __shared__ float Bs[32][68];
  int tid = threadIdx.x;
  int m0 = blockIdx.x * 64, n0 = blockIdx.y * 64;
  int tx = tid & 15, ty = tid >> 4;
  float acc[4][4] = {};

  for (int k0 = 0; k0 < K; k0 += 32) {
    #pragma unroll
    for (int p = 0; p < 2; ++p) {
      int row = (tid >> 3) + p*32;
      int kq  = (tid & 7) * 4;
      int gmr = m0 + row, gk = k0 + kq;
      float4 v = make_float4(0.f,0.f,0.f,0.f);
      if (gmr < M) {
        if (gk + 3 < K) v = *(const float4*)&A[gmr*K + gk];
        else {
          float* pv = (float*)&v;
          for (int q = 0; q < 4; ++q) if (gk + q < K) pv[q] = A[gmr*K + gk + q];
        }
      }
      As[kq+0][row]=v.x; As[kq+1][row]=v.y; As[kq+2][row]=v.z; As[kq+3][row]=v.w;
    }
    #pragma unroll
    for (int p = 0; p < 8; ++p) {
      int row = (tid >> 6) + p*4;
      int col = tid & 63;
      int gk = k0 + row, gn = n0 + col;
      float v = 0.f;
      if (gk < K && gn < N) v = B[gk*N + gn];
      Bs[row][col] = v;
    }
    __syncthreads();
    #pragma unroll
    for (int kk = 0; kk < 32; ++kk) {
      float4 a = *(const float4*)&As[kk][ty*4];
      float4 b = *(const float4*)&Bs[kk][tx*4];
      acc[0][0] += a.x*b.x; acc[0][1] += a.x*b.y; acc[0][2] += a.x*b.z; acc[0][3] += a.x*b.w;
      acc[1][0] += a.y*b.x; acc[1][1] += a.y*b.y; acc[1][2] += a.y*b.z; acc[1][3] += a.y*b.w;
      acc[2][0] += a.z*b.x; acc[2][1] += a.z*b.y; acc[2][2] += a.z*b.z; acc[2][3] += a.z*b.w;
      acc[3][0] += a.w*b.x; acc[3][1] += a.w*b.y; acc[3][2] += a.w*b.z; acc[3][3] += a.w*b.w;
    }
    __syncthreads();
  }
  #pragma unroll
  for (int i = 0; i < 4; ++i) {
    int gmr = m0 + ty*4 + i;
    if (gmr >= M) continue;
    #pragma unroll
    for (int j = 0; j < 4; ++j) {
      int gn = n0 + tx*4 + j;
      if (gn >= N) continue;
      float c = acc[i][j];
      if (EPIL == 1) {
        c += bias[gn];
        float s = bng[gn] * rsqrtf(bnv[gn] + EPSV);
        c = (c - bnm[gn]) * s + bnb[gn];
        c = fmaxf(c, 0.f);
      }
      C[gmr*N + gn] = c;
    }
  }
}

// ---------------- CSR build ----------------
__global__ __launch_bounds__(256) void hist_k(const int* __restrict__ dst, int* __restrict__ deg){
  int e = blockIdx.x*256 + threadIdx.x;
  if (e < NE) atomicAdd(&deg[dst[e]], 1);
}

// per-block exclusive scan of 1024 elements; bsum[b] = block total
__global__ __launch_bounds__(256) void scan1_k(const int* __restrict__ deg, int* __restrict__ part,
                                               int* __restrict__ bsum, int n){
  __shared__ int lds[256];
  int t = threadIdx.x;
  int base = blockIdx.x * SCAN_B + t*4;
  int v[4]; int s = 0;
  #pragma unroll
  for (int q = 0; q < 4; ++q){ int idx = base+q; v[q] = (idx < n) ? deg[idx] : 0; s += v[q]; }
  lds[t] = s;
  __syncthreads();
  for (int off = 1; off < 256; off <<= 1){
    int val = 0;
    if (t >= off) val = lds[t-off];
    __syncthreads();
    if (t >= off) lds[t] += val;
    __syncthreads();
  }
  if (t == 255) bsum[blockIdx.x] = lds[255];
  int run = (t == 0) ? 0 : lds[t-1];
  #pragma unroll
  for (int q = 0; q < 4; ++q){ int idx = base+q; if (idx < n) part[idx] = run; run += v[q]; }
}

// single-block exclusive scan of the (<=128) block sums
__global__ void scan2_k(int* __restrict__ bsum, int nb){
  __shared__ int lds[128];
  int t = threadIdx.x;
  int v = (t < nb) ? bsum[t] : 0;
  lds[t] = v;
  __syncthreads();
  for (int off = 1; off < 128; off <<= 1){
    int val = 0;
    if (t >= off) val = lds[t-off];
    __syncthreads();
    if (t >= off) lds[t] += val;
    __syncthreads();
  }
  if (t < nb) bsum[t] = (t == 0) ? 0 : lds[t-1];
}

// final: rowptr[i] = part[i] + bsum[i/1024]; also cpos copy and rowptr[NN]=NE
__global__ __launch_bounds__(256) void scan3_k(const int* __restrict__ part, const int* __restrict__ bsum,
                                               int* __restrict__ rowptr, int* __restrict__ cpos, int n){
  int i = blockIdx.x*256 + threadIdx.x;
  if (i < n){
    int v = part[i] + bsum[i >> 10];
    rowptr[i] = v;
    cpos[i] = v;
  }
  if (i == 0) rowptr[n] = NE;
}

__global__ __launch_bounds__(256) void fill_k(const int* __restrict__ src, const int* __restrict__ dst,
                                              int* __restrict__ cpos, int* __restrict__ elist){
  int e = blockIdx.x*256 + threadIdx.x;
  if (e < NE){
    int p = atomicAdd(&cpos[dst[e]], 1);
    elist[p] = src[e];
  }
}

// ---------------- gather: agg[n] = sum over in-edges of m[src] ----------------
__global__ __launch_bounds__(256) void gather_k(const float* __restrict__ m,
                                                const int* __restrict__ rowptr,
                                                const int* __restrict__ elist,
                                                float* __restrict__ agg){
  int n = blockIdx.x;
  int beg = rowptr[n], end = rowptr[n+1];
  int j = threadIdx.x;
  float acc = 0.f;
  for (int k = beg; k < end; ++k){
    int s = elist[k];              // uniform across block -> broadcast
    if (j < H) acc += m[(size_t)s*H + j];
  }
  if (j < H) agg[(size_t)n*H + j] = acc;
}

// ---------------- fused GRU cell ----------------
__global__ __launch_bounds__(256) void gru_k(
    const float* __restrict__ agg, const float* __restrict__ h,
    const float* __restrict__ wihT, const float* __restrict__ whhT,  // [200][600]
    const float* __restrict__ bih, const float* __restrict__ bhh,
    float* __restrict__ hout)
{
  __shared__ float a_lds[32][H];
  __shared__ float h_lds[32][H];
  int tid = threadIdx.x;
  int n0 = blockIdx.x * 32;
  for (int idx = tid; idx < 32*H; idx += 256) {
    int r = idx / H, c = idx - r*H;
    a_lds[r][c] = agg[(size_t)(n0 + r)*H + c];
    h_lds[r][c] = h  [(size_t)(n0 + r)*H + c];
  }
  __syncthreads();
  int tj = tid & 63, tn = tid >> 6;
  int j = blockIdx.y * 64 + tj;
  int jc = (j < H) ? j : 0;
  float aIR[8]={},aIZ[8]={},aIN[8]={},aHR[8]={},aHZ[8]={},aHN[8]={};
  for (int k = 0; k < H; k += 2) {
    float wi0a = wihT[(k  )*600 +       jc], wi1a = wihT[(k  )*600 + 200 + jc], wi2a = wihT[(k  )*600 + 400 + jc];
    float wi0b = wihT[(k+1)*600 +       jc], wi1b = wihT[(k+1)*600 + 200 + jc], wi2b = wihT[(k+1)*600 + 400 + jc];
    float wh0a = whhT[(k  )*600 +       jc], wh1a = whhT[(k  )*600 + 200 + jc], wh2a = whhT[(k  )*600 + 400 + jc];
    float wh0b = whhT[(k+1)*600 +       jc], wh1b = whhT[(k+1)*600 + 200 + jc], wh2b = whhT[(k+1)*600 + 400 + jc];
    #pragma unroll
    for (int r = 0; r < 8; ++r) {
      float2 a  = *(const float2*)&a_lds[tn*8 + r][k];
      float2 hh = *(const float2*)&h_lds[tn*8 + r][k];
      aIR[r] += a.x*wi0a + a.y*wi0b;
      aIZ[r] += a.x*wi1a + a.y*wi1b;
      aIN[r] += a.x*wi2a + a.y*wi2b;
      aHR[r] += hh.x*wh0a + hh.y*wh0b;
      aHZ[r] += hh.x*wh1a + hh.y*wh1b;
      aHN[r] += hh.x*wh2a + hh.y*wh2b;
    }
  }
  if (j < H) {
    float bir = bih[j], biz = bih[200+j], bin = bih[400+j];
    float bhr = bhh[j], bhz = bhh[200+j], bhn = bhh[400+j];
    #pragma unroll
    for (int r = 0; r < 8; ++r) {
      int node = n0 + tn*8 + r;
      float rg = sigm(aIR[r] + bir + aHR[r] + bhr);
      float zg = sigm(aIZ[r] + biz + aHZ[r] + bhz);
      float ng = tanhf(aIN[r] + bin + rg*(aHN[r] + bhn));
      float ho = h_lds[tn*8 + r][j];
      hout[(size_t)node*H + j] = (1.f - zg)*ng + zg*ho;
    }
  }
}

// ---------------- pooling ----------------
__global__ __launch_bounds__(256) void pool_k(
    const float* __restrict__ h, const int* __restrict__ batch,
    const float* __restrict__ g2, const float* __restrict__ b2,
    const float* __restrict__ m2, const float* __restrict__ v2,
    float* __restrict__ gsum, float* __restrict__ gmax)
{
  long tid = (long)blockIdx.x*256 + threadIdx.x;
  if (tid >= (long)NN*H) return;
  int n = (int)(tid / H), j = (int)(tid - (long)n*H);
  float s = g2[j] * rsqrtf(v2[j] + EPSV);
  float val = (h[tid] - m2[j]) * s + b2[j];
  val = fmaxf(val, 0.f);
  int b = batch[n];
  unsafeAtomicAdd(&gsum[b*H + j], val);
  atomicMax((int*)&gmax[b*H + j], __float_as_int(val));
}

__global__ void cnt_k(const int* __restrict__ batch, float* __restrict__ cnt){
  int g = blockIdx.x*64 + threadIdx.x;
  if (g >= NG) return;
  int lo = 0, hi = NN;
  while (lo < hi){ int mid = (lo+hi)>>1; if (batch[mid] < g) lo = mid+1; else hi = mid; }
  int lo2 = lo, hi2 = NN;
  while (lo2 < hi2){ int mid = (lo2+hi2)>>1; if (batch[mid] < g+1) lo2 = mid+1; else hi2 = mid; }
  cnt[g] = (float)(lo2 - lo);
}

__global__ __launch_bounds__(256) void fc1_k(
    const float* __restrict__ gsum, const float* __restrict__ gmax,
    const float* __restrict__ cnt, const float* __restrict__ W,
    const float* __restrict__ bias,
    const float* __restrict__ fg, const float* __restrict__ fb,
    const float* __restrict__ fm, const float* __restrict__ fv,
    float* __restrict__ out)
{
  int tid = blockIdx.x*256 + threadIdx.x;
  if (tid >= NG*H) return;
  int g = tid / H, j = tid - g*H;
  float inv = 1.f / fmaxf(cnt[g], 1.f);
  const float* wr = W + j*2*H;
  float acc = bias[j];
  for (int k = 0; k < H; ++k) acc += gsum[g*H + k]*inv * wr[k];
  for (int k = 0; k < H; ++k) acc += gmax[g*H + k] * wr[H + k];
  float s = fg[j] * rsqrtf(fv[j] + EPSV);
  acc = (acc - fm[j]) * s + fb[j];
  out[tid] = fmaxf(acc, 0.f);
}

__global__ void fc2_k(const float* __restrict__ in, const float* __restrict__ W,
                      const float* __restrict__ bias, float* __restrict__ out)
{
  int tid = blockIdx.x*256 + threadIdx.x;
  if (tid >= NG*2) return;
  int g = tid >> 1, c = tid & 1;
  float acc = bias[c];
  const float* wr = W + c*H;
  const float* xr = in + g*H;
  for (int k = 0; k < H; ++k) acc += xr[k]*wr[k];
  out[tid] = acc;
}

extern "C" void kernel_launch(void* const* d_in, const int* in_sizes, int n_in,
                              void* d_out, int out_size, void* d_ws, size_t ws_size,
                              hipStream_t stream)
{
  const float* x     = (const float*)d_in[0];
  const int*   eidx  = (const int*)d_in[1];
  const int*   batch = (const int*)d_in[2];
  const float* projW = (const float*)d_in[3];
  const float* projb = (const float*)d_in[4];
  const float* bn1g  = (const float*)d_in[5];
  const float* bn1b  = (const float*)d_in[6];
  const float* bn1m  = (const float*)d_in[7];
  const float* bn1v  = (const float*)d_in[8];
  const float* bn2g  = (const float*)d_in[9];
  const float* bn2b  = (const float*)d_in[10];
  const float* bn2m  = (const float*)d_in[11];
  const float* bn2v  = (const float*)d_in[12];
  const float* bnfg  = (const float*)d_in[13];
  const float* bnfb  = (const float*)d_in[14];
  const float* bnfm  = (const float*)d_in[15];
  const float* bnfv  = (const float*)d_in[16];
  const float* ggcW  = (const float*)d_in[17];
  const float* wih   = (const float*)d_in[18];
  const float* whh   = (const float*)d_in[19];
  const float* bih   = (const float*)d_in[20];
  const float* bhh   = (const float*)d_in[21];
  const float* fc1W  = (const float*)d_in[22];
  const float* fc1b  = (const float*)d_in[23];
  const float* fc2W  = (const float*)d_in[24];
  const float* fc2b  = (const float*)d_in[25];

  char* wsp = (char*)d_ws;
  auto alloc = [&](size_t nbytes) {
    char* p = wsp;
    wsp += ((nbytes + 255) / 256) * 256;
    return (void*)p;
  };
  float* buf0  = (float*)alloc((size_t)NN*H*4);
  float* buf1  = (float*)alloc((size_t)NN*H*4);
  float* agg   = (float*)alloc((size_t)NN*H*4);
  float* projT = (float*)alloc((size_t)D*H*4);
  float* wihT  = (float*)alloc((size_t)H*3*H*4);
  float* whhT  = (float*)alloc((size_t)H*3*H*4);
  float* gsum  = (float*)alloc((size_t)NG*H*4);
  float* gmax  = (float*)alloc((size_t)NG*H*4);
  float* cnt   = (float*)alloc(NG*4);
  float* fc1o  = (float*)alloc((size_t)NG*H*4);
  // CSR scratch
  const int NB = (NN + SCAN_B - 1) / SCAN_B;
  int* deg    = (int*)alloc((size_t)NN*4);
  int* part   = (int*)alloc((size_t)NN*4);
  int* bsum   = (int*)alloc((size_t)NB*4);
  int* rowptr = (int*)alloc((size_t)(NN+1)*4);
  int* cpos   = (int*)alloc((size_t)NN*4);
  int* elist  = (int*)alloc((size_t)NE*4);

  const int* srcp = eidx;
  const int* dstp = eidx + NE;

  // ---- CSR build (once; reused for all 3 GGC steps) ----
  hipMemsetAsync(deg, 0, (size_t)NN*4, stream);
  hist_k<<<(NE + 255)/256, 256, 0, stream>>>(dstp, deg);
  scan1_k<<<NB, 256, 0, stream>>>(deg, part, bsum, NN);
  scan2_k<<<1, 128, 0, stream>>>(bsum, NB);
  scan3_k<<<(NN + 255)/256, 256, 0, stream>>>(part, bsum, rowptr, cpos, NN);
  fill_k<<<(NE + 255)/256, 256, 0, stream>>>(srcp, dstp, cpos, elist);

  // ---- weight transposes ----
  ktrans<<<(H*D + 255)/256, 256, 0, stream>>>(projW, projT, H, D);
  ktrans<<<(3*H*H + 255)/256, 256, 0, stream>>>(wih, wihT, 3*H, H);
  ktrans<<<(3*H*H + 255)/256, 256, 0, stream>>>(whh, whhT, 3*H, H);

  dim3 gproj((NN + 63)/64, (H + 63)/64);
  gemm_k<1><<<gproj, 256, 0, stream>>>(x, projT, projb, bn1g, bn1b, bn1m, bn1v,
                                       buf0, NN, H, D);

  float* hcur = buf0; float* hoth = buf1;
  for (int i = 0; i < 3; ++i) {
    gemm_k<0><<<gproj, 256, 0, stream>>>(hcur, ggcW + (size_t)i*H*H,
                                         nullptr, nullptr, nullptr, nullptr, nullptr,
                                         hoth, NN, H, H);
    gather_k<<<NN, 256, 0, stream>>>(hoth, rowptr, elist, agg);
    gru_k<<<dim3(NN/32, 4), 256, 0, stream>>>(agg, hcur, wihT, whhT, bih, bhh, hoth);
    float* t = hcur; hcur = hoth; hoth = t;
  }

  hipMemsetAsync(gsum, 0, (size_t)NG*H*4, stream);
  hipMemsetAsync(gmax, 0, (size_t)NG*H*4, stream);
  pool_k<<<(int)(((long)NN*H + 255)/256), 256, 0, stream>>>(hcur, batch,
                                                            bn2g, bn2b, bn2m, bn2v,
                                                            gsum, gmax);
  cnt_k<<<(NG + 63)/64, 64, 0, stream>>>(batch, cnt);
  fc1_k<<<(NG*H + 255)/256, 256, 0, stream>>>(gsum, gmax, cnt, fc1W, fc1b,
                                              bnfg, bnfb, bnfm, bnfv, fc1o);
  fc2_k<<<(NG*2 + 255)/256, 256, 0, stream>>>(fc1o, fc2W, fc2b, (float*)d_out);
}

// Round 4
// 2796.649 us; speedup vs baseline: 6.8700x; 2.2235x over previous
//
#include <hip/hip_runtime.h>
#include <cmath>

#define NN 100000
#define NE 1600000
#define NG 512
#define H 200
#define D 205
#define EPSV 1e-5f
#define SCAN_B 1024
#define KP 224    // padded K extent for weight (B-side) buffers, bf16, zero-padded
#define LPX 208   // x copy pitch (fp32, 16B-multiple)

typedef __attribute__((ext_vector_type(8))) short short8v;
typedef __attribute__((ext_vector_type(4))) float f32x4;

#define MFMA16(a,b,c) __builtin_amdgcn_mfma_f32_16x16x32_bf16(a,b,c,0,0,0)

static __device__ __forceinline__ float sigm(float x){ return 1.0f/(1.0f+expf(-x)); }

// split fp32 -> bf16 hi (truncate) + bf16 lo (residual)
static __device__ __forceinline__ void split2(float x, unsigned short& h, unsigned short& l){
  unsigned xb = __float_as_uint(x);
  h = (unsigned short)(xb >> 16);
  float hf = __uint_as_float(xb & 0xffff0000u);
  l = (unsigned short)(__float_as_uint(x - hf) >> 16);
}

static __device__ __forceinline__ void splitv(float4 v0, float4 v1, short8v& hi, short8v& lo){
  float v[8] = {v0.x,v0.y,v0.z,v0.w,v1.x,v1.y,v1.z,v1.w};
  #pragma unroll
  for (int e = 0; e < 8; ++e){
    unsigned u = __float_as_uint(v[e]);
    hi[e] = (short)(u >> 16);
    float hf = __uint_as_float(u & 0xffff0000u);
    lo[e] = (short)(__float_as_uint(v[e] - hf) >> 16);
  }
}

static __device__ __forceinline__ void gload16(const void* src, void* dst){
  __builtin_amdgcn_global_load_lds(
      (const __attribute__((address_space(1))) unsigned int*)src,
      (__attribute__((address_space(3))) unsigned int*)dst, 16, 0, 0);
}

// ---------------- pad-copy x: [NN,205] fp32 -> [NN,208] fp32 ----------------
__global__ __launch_bounds__(256) void padx_k(const float* __restrict__ in, float* __restrict__ out){
  long i = (long)blockIdx.x*256 + threadIdx.x;
  if (i >= (long)NN*LPX) return;
  int r = (int)(i/LPX), c = (int)(i - (long)r*LPX);
  out[i] = (c < D) ? in[(size_t)r*D + c] : 0.f;
}

// ---------------- weight cvt: fp32 [rows,C] -> hi/lo bf16 [rows,KP], zero-padded ----------------
__global__ __launch_bounds__(256) void cvt_split(const float* __restrict__ in,
    unsigned short* __restrict__ hi, unsigned short* __restrict__ lo, int rows, int C){
  long i = (long)blockIdx.x*256 + threadIdx.x;
  long tot = (long)rows*KP;
  if (i >= tot) return;
  int r = (int)(i/KP), c = (int)(i - (long)r*KP);
  float v = (c < C) ? in[(size_t)r*C + c] : 0.f;
  unsigned short hh, ll; split2(v,hh,ll);
  hi[i] = hh; lo[i] = ll;
}

// ---------------- weight cvt + transpose: out[n][k]=in[k][n], [C,KP], zero-padded ----------------
__global__ __launch_bounds__(256) void cvt_tsplit(const float* __restrict__ in,
    unsigned short* __restrict__ hi, unsigned short* __restrict__ lo, int R, int C){
  int i = blockIdx.x*256 + threadIdx.x;
  if (i >= C*KP) return;
  int n = i/KP, k = i - n*KP;
  float v = (k < R) ? in[(size_t)k*C + n] : 0.f;
  unsigned short hh, ll; split2(v,hh,ll);
  hi[i] = hh; lo[i] = ll;
}

// ---------------- split-bf16 MFMA GEMM: C[M,N] = A(fp32) @ Bsplit^T ----------------
// A fp32 row pitch LP (16B mult); Bhi/Blo [N,KP] bf16, zero pad k>=K kills A tail garbage.
template<int EPIL>
__global__ __launch_bounds__(256) void mgemm(
    const float* __restrict__ A, int LP,
    const unsigned short* __restrict__ Bhi, const unsigned short* __restrict__ Blo,
    int M, int N,
    const float* __restrict__ bias,
    const float* __restrict__ bg, const float* __restrict__ bb,
    const float* __restrict__ bm, const float* __restrict__ bv,
    float* __restrict__ C)
{
  __shared__ __align__(16) float As[128*32];            // XOR-swizzled image
  __shared__ __align__(16) unsigned short Bs[2][128*32];// linear [row][32k]
  const int tid = threadIdx.x, lane = tid & 63, wave = tid >> 6;
  const int r0 = blockIdx.x*128, n0 = blockIdx.y*128;
  const int wr = (wave>>1)*64, wc = (wave&1)*64;
  const int fr = lane & 15, fq = lane >> 4;
  f32x4 acc[4][4] = {};

  for (int k0 = 0; k0 < KP; k0 += 32) {
    for (int p = wave; p < 32; p += 4) {
      if (p < 16) {                      // A: 16 chunks of 1KB
        int R = p*8 + (lane>>3), c = lane&7;
        int csw = c ^ (R&7);             // source pre-swizzle (16B granules)
        int rg = r0 + R; if (rg > M-1) rg = M-1;
        gload16(A + (size_t)rg*LP + k0 + csw*4, (char*)As + p*1024);
      } else {                           // B hi/lo: 8 chunks each
        int pb = p & 7;
        const unsigned short* sp = (p < 24) ? Bhi : Blo;
        int R = pb*16 + (lane>>2), q = lane&3;
        int rg = n0 + R; if (rg > N-1) rg = N-1;
        gload16(sp + (size_t)rg*KP + k0 + q*8, (char*)Bs[p>=24] + pb*1024);
      }
    }
    __syncthreads();
    short8v ah[4], al[4], bh[4], bl[4];
    #pragma unroll
    for (int t = 0; t < 4; ++t) {
      int row = wr + t*16 + fr;
      const char* base = (const char*)As + row*128;
      float4 v0 = *(const float4*)(base + (((fq*32)    ) ^ ((row&7)<<4)));
      float4 v1 = *(const float4*)(base + (((fq*32)+16 ) ^ ((row&7)<<4)));
      splitv(v0, v1, ah[t], al[t]);
      int rowb = wc + t*16 + fr;
      bh[t] = *(const short8v*)((const char*)Bs[0] + rowb*64 + fq*16);
      bl[t] = *(const short8v*)((const char*)Bs[1] + rowb*64 + fq*16);
    }
    #pragma unroll
    for (int i = 0; i < 4; ++i)
      #pragma unroll
      for (int j = 0; j < 4; ++j) {
        acc[i][j] = MFMA16(ah[i], bh[j], acc[i][j]);
        acc[i][j] = MFMA16(ah[i], bl[j], acc[i][j]);
        acc[i][j] = MFMA16(al[i], bh[j], acc[i][j]);
      }
    __syncthreads();
  }

  #pragma unroll
  for (int i = 0; i < 4; ++i)
    #pragma unroll
    for (int j = 0; j < 4; ++j)
      #pragma unroll
      for (int q = 0; q < 4; ++q) {
        int row = r0 + wr + i*16 + fq*4 + q;
        int col = n0 + wc + j*16 + fr;
        if (row < M && col < N) {
          float c = acc[i][j][q];
          if (EPIL) {
            c += bias[col];
            c = (c - bm[col]) * (bg[col] * rsqrtf(bv[col] + EPSV)) + bb[col];
            c = fmaxf(c, 0.f);
          }
          C[(size_t)row*N + col] = c;
        }
      }
}

// ---------------- fused GRU: 6 gate-GEMMs (MFMA) + elementwise ----------------
// Reads agg + hprev (fp32, pitch H), writes hnew (different buffer, no race).
__global__ __launch_bounds__(256) void gru6(
    const float* __restrict__ agg, const float* __restrict__ hprev,
    const unsigned short* __restrict__ Wihh, const unsigned short* __restrict__ Wihl, // [600,KP]
    const unsigned short* __restrict__ Whhh, const unsigned short* __restrict__ Whhl,
    const float* __restrict__ bih, const float* __restrict__ bhh,
    float* __restrict__ hnew)
{
  __shared__ __align__(16) float Gs[128*32];
  __shared__ __align__(16) float Hs[128*32];
  __shared__ __align__(16) unsigned short Ws[2][192*32];  // [hi/lo][gate*32+jj][k]
  const int tid = threadIdx.x, lane = tid & 63, wave = tid >> 6;
  const int r0 = blockIdx.x*128, j0 = blockIdx.y*32;
  const int fr = lane & 15, fq = lane >> 4;
  f32x4 acc[6][2][2] = {};   // [gate][row-sub][col-sub]

  for (int k0 = 0; k0 < KP; k0 += 32) {
    for (int p = wave; p < 56; p += 4) {
      if (p < 32) {                        // A regions: agg(16) + h(16)
        int pa = p & 15;
        const float* sp = (p < 16) ? agg : hprev;
        char* base = (p < 16) ? (char*)Gs : (char*)Hs;
        int R = pa*8 + (lane>>3), c = lane&7;
        int csw = c ^ (R&7);
        int rg = r0 + R; if (rg > NN-1) rg = NN-1;
        gload16(sp + (size_t)rg*H + k0 + csw*4, base + pa*1024);
      } else {                             // W: hi 12 chunks, lo 12 chunks
        int pw = p - 32;
        int comp = pw / 12; pw -= comp*12;
        int R = pw*16 + (lane>>2), q = lane&3;
        int gate = R >> 5, jj = R & 31;
        int g3 = (gate >= 3) ? gate-3 : gate;
        int jcol = j0 + jj; if (jcol > H-1) jcol = H-1;
        const unsigned short* sp = (gate < 3) ? (comp ? Wihl : Wihh)
                                              : (comp ? Whhl : Whhh);
        gload16(sp + (size_t)(g3*H + jcol)*KP + k0 + q*8, (char*)Ws[comp] + pw*1024);
      }
    }
    __syncthreads();
    short8v gh[2], gl[2], hh[2], hl[2];
    #pragma unroll
    for (int t = 0; t < 2; ++t) {
      int row = wave*32 + t*16 + fr;
      const char* gb = (const char*)Gs + row*128;
      const char* hb = (const char*)Hs + row*128;
      int s0 = ((fq*32)   ) ^ ((row&7)<<4);
      int s1 = ((fq*32)+16) ^ ((row&7)<<4);
      splitv(*(const float4*)(gb+s0), *(const float4*)(gb+s1), gh[t], gl[t]);
      splitv(*(const float4*)(hb+s0), *(const float4*)(hb+s1), hh[t], hl[t]);
    }
    #pragma unroll
    for (int g = 0; g < 6; ++g) {
      short8v b0h = *(const short8v*)((const char*)Ws[0] + (g*32      + fr)*64 + fq*16);
      short8v b1h = *(const short8v*)((const char*)Ws[0] + (g*32 + 16 + fr)*64 + fq*16);
      short8v b0l = *(const short8v*)((const char*)Ws[1] + (g*32      + fr)*64 + fq*16);
      short8v b1l = *(const short8v*)((const char*)Ws[1] + (g*32 + 16 + fr)*64 + fq*16);
      #pragma unroll
      for (int t = 0; t < 2; ++t) {
        short8v a_h = (g < 3) ? gh[t] : hh[t];
        short8v a_l = (g < 3) ? gl[t] : hl[t];
        acc[g][t][0] = MFMA16(a_h, b0h, acc[g][t][0]);
        acc[g][t][0] = MFMA16(a_h, b0l, acc[g][t][0]);
        acc[g][t][0] = MFMA16(a_l, b0h, acc[g][t][0]);
        acc[g][t][1] = MFMA16(a_h, b1h, acc[g][t][1]);
        acc[g][t][1] = MFMA16(a_h, b1l, acc[g][t][1]);
        acc[g][t][1] = MFMA16(a_l, b1h, acc[g][t][1]);
      }
    }
    __syncthreads();
  }

  #pragma unroll
  for (int ct = 0; ct < 2; ++ct) {
    int j = j0 + ct*16 + fr;
    if (j >= H) continue;
    float br  = bih[j]     + bhh[j];
    float bz  = bih[H+j]   + bhh[H+j];
    float bin = bih[2*H+j], bhn = bhh[2*H+j];
    #pragma unroll
    for (int t = 0; t < 2; ++t)
      #pragma unroll
      for (int q = 0; q < 4; ++q) {
        int row = r0 + wave*32 + t*16 + fq*4 + q;
        if (row >= NN) continue;
        float ir = acc[0][t][ct][q], iz = acc[1][t][ct][q], inn = acc[2][t][ct][q];
        float hr = acc[3][t][ct][q], hz = acc[4][t][ct][q], hn  = acc[5][t][ct][q];
        float r = sigm(ir + hr + br);
        float z = sigm(iz + hz + bz);
        float n = tanhf(inn + bin + r*(hn + bhn));
        size_t o = (size_t)row*H + j;
        float ho = hprev[o];
        hnew[o] = (1.f - z)*n + z*ho;
      }
  }
}

// ---------------- CSR build ----------------
__global__ __launch_bounds__(256) void hist_k(const int* __restrict__ dst, int* __restrict__ deg){
  int e = blockIdx.x*256 + threadIdx.x;
  if (e < NE) atomicAdd(&deg[dst[e]], 1);
}

__global__ __launch_bounds__(256) void scan1_k(const int* __restrict__ deg, int* __restrict__ part,
                                               int* __restrict__ bsum, int n){
  __shared__ int lds[256];
  int t = threadIdx.x;
  int base = blockIdx.x * SCAN_B + t*4;
  int v[4]; int s = 0;
  #pragma unroll
  for (int q = 0; q < 4; ++q){ int idx = base+q; v[q] = (idx < n) ? deg[idx] : 0; s += v[q]; }
  lds[t] = s;
  __syncthreads();
  for (int off = 1; off < 256; off <<= 1){
    int val = 0;
    if (t >= off) val = lds[t-off];
    __syncthreads();
    if (t >= off) lds[t] += val;
    __syncthreads();
  }
  if (t == 255) bsum[blockIdx.x] = lds[255];
  int run = (t == 0) ? 0 : lds[t-1];
  #pragma unroll
  for (int q = 0; q < 4; ++q){ int idx = base+q; if (idx < n) part[idx] = run; run += v[q]; }
}

__global__ void scan2_k(int* __restrict__ bsum, int nb){
  __shared__ int lds[128];
  int t = threadIdx.x;
  int v = (t < nb) ? bsum[t] : 0;
  lds[t] = v;
  __syncthreads();
  for (int off = 1; off < 128; off <<= 1){
    int val = 0;
    if (t >= off) val = lds[t-off];
    __syncthreads();
    if (t >= off) lds[t] += val;
    __syncthreads();
  }
  if (t < nb) bsum[t] = (t == 0) ? 0 : lds[t-1];
}

__global__ __launch_bounds__(256) void scan3_k(const int* __restrict__ part, const int* __restrict__ bsum,
                                               int* __restrict__ rowptr, int* __restrict__ cpos, int n){
  int i = blockIdx.x*256 + threadIdx.x;
  if (i < n){
    int v = part[i] + bsum[i >> 10];
    rowptr[i] = v;
    cpos[i] = v;
  }
  if (i == 0) rowptr[n] = NE;
}

__global__ __launch_bounds__(256) void fill_k(const int* __restrict__ src, const int* __restrict__ dst,
                                              int* __restrict__ cpos, int* __restrict__ elist){
  int e = blockIdx.x*256 + threadIdx.x;
  if (e < NE){
    int p = atomicAdd(&cpos[dst[e]], 1);
    elist[p] = src[e];
  }
}

// ---------------- gather: agg[n] = sum over in-edges of m[src] (fp32) ----------------
__global__ __launch_bounds__(256) void gather_k(const float* __restrict__ m,
                                                const int* __restrict__ rowptr,
                                                const int* __restrict__ elist,
                                                float* __restrict__ agg){
  int n = blockIdx.x;
  int beg = rowptr[n], end = rowptr[n+1];
  int j = threadIdx.x;
  float acc = 0.f;
  if (j < H)
    for (int k = beg; k < end; ++k){
      int s = elist[k];
      acc += m[(size_t)s*H + j];
    }
  if (j < H) agg[(size_t)n*H + j] = acc;
}

// ---------------- pooling ----------------
__global__ __launch_bounds__(256) void pool_k(
    const float* __restrict__ h, const int* __restrict__ batch,
    const float* __restrict__ g2, const float* __restrict__ b2,
    const float* __restrict__ m2, const float* __restrict__ v2,
    float* __restrict__ gsum, float* __restrict__ gmax)
{
  long tid = (long)blockIdx.x*256 + threadIdx.x;
  if (tid >= (long)NN*H) return;
  int n = (int)(tid / H), j = (int)(tid - (long)n*H);
  float s = g2[j] * rsqrtf(v2[j] + EPSV);
  float val = (h[tid] - m2[j]) * s + b2[j];
  val = fmaxf(val, 0.f);
  int b = batch[n];
  unsafeAtomicAdd(&gsum[b*H + j], val);
  atomicMax((int*)&gmax[b*H + j], __float_as_int(val));
}

__global__ void cnt_k(const int* __restrict__ batch, float* __restrict__ cnt){
  int g = blockIdx.x*64 + threadIdx.x;
  if (g >= NG) return;
  int lo = 0, hi = NN;
  while (lo < hi){ int mid = (lo+hi)>>1; if (batch[mid] < g) lo = mid+1; else hi = mid; }
  int lo2 = lo, hi2 = NN;
  while (lo2 < hi2){ int mid = (lo2+hi2)>>1; if (batch[mid] < g+1) lo2 = mid+1; else hi2 = mid; }
  cnt[g] = (float)(lo2 - lo);
}

__global__ __launch_bounds__(256) void fc1_k(
    const float* __restrict__ gsum, const float* __restrict__ gmax,
    const float* __restrict__ cnt, const float* __restrict__ W,
    const float* __restrict__ bias,
    const float* __restrict__ fg, const float* __restrict__ fb,
    const float* __restrict__ fm, const float* __restrict__ fv,
    float* __restrict__ out)
{
  int tid = blockIdx.x*256 + threadIdx.x;
  if (tid >= NG*H) return;
  int g = tid / H, j = tid - g*H;
  float inv = 1.f / fmaxf(cnt[g], 1.f);
  const float* wr = W + j*2*H;
  float acc = bias[j];
  for (int k = 0; k < H; ++k) acc += gsum[g*H + k]*inv * wr[k];
  for (int k = 0; k < H; ++k) acc += gmax[g*H + k] * wr[H + k];
  float s = fg[j] * rsqrtf(fv[j] + EPSV);
  acc = (acc - fm[j]) * s + fb[j];
  out[tid] = fmaxf(acc, 0.f);
}

__global__ void fc2_k(const float* __restrict__ in, const float* __restrict__ W,
                      const float* __restrict__ bias, float* __restrict__ out)
{
  int tid = blockIdx.x*256 + threadIdx.x;
  if (tid >= NG*2) return;
  int g = tid >> 1, c = tid & 1;
  float acc = bias[c];
  const float* wr = W + c*H;
  const float* xr = in + g*H;
  for (int k = 0; k < H; ++k) acc += xr[k]*wr[k];
  out[tid] = acc;
}

extern "C" void kernel_launch(void* const* d_in, const int* in_sizes, int n_in,
                              void* d_out, int out_size, void* d_ws, size_t ws_size,
                              hipStream_t stream)
{
  const float* x     = (const float*)d_in[0];
  const int*   eidx  = (const int*)d_in[1];
  const int*   batch = (const int*)d_in[2];
  const float* projW = (const float*)d_in[3];
  const float* projb = (const float*)d_in[4];
  const float* bn1g  = (const float*)d_in[5];
  const float* bn1b  = (const float*)d_in[6];
  const float* bn1m  = (const float*)d_in[7];
  const float* bn1v  = (const float*)d_in[8];
  const float* bn2g  = (const float*)d_in[9];
  const float* bn2b  = (const float*)d_in[10];
  const float* bn2m  = (const float*)d_in[11];
  const float* bn2v  = (const float*)d_in[12];
  const float* bnfg  = (const float*)d_in[13];
  const float* bnfb  = (const float*)d_in[14];
  const float* bnfm  = (const float*)d_in[15];
  const float* bnfv  = (const float*)d_in[16];
  const float* ggcW  = (const float*)d_in[17];
  const float* wih   = (const float*)d_in[18];
  const float* whh   = (const float*)d_in[19];
  const float* bih   = (const float*)d_in[20];
  const float* bhh   = (const float*)d_in[21];
  const float* fc1W  = (const float*)d_in[22];
  const float* fc1b  = (const float*)d_in[23];
  const float* fc2W  = (const float*)d_in[24];
  const float* fc2b  = (const float*)d_in[25];

  char* wsp = (char*)d_ws;
  auto alloc = [&](size_t nbytes) {
    char* p = wsp;
    wsp += ((nbytes + 255) / 256) * 256;
    return (void*)p;
  };
  // three rotating fp32 node buffers (bufB oversized for the 208-pitch x copy)
  float* bufA = (float*)alloc((size_t)NN*H*4);
  float* bufB = (float*)alloc((size_t)NN*LPX*4);
  float* bufC = (float*)alloc((size_t)NN*H*4);
  // weights (bf16 split, zero-padded to KP) — also the finite "tail" after bufC
  unsigned short* pBh   = (unsigned short*)alloc((size_t)H*KP*2);
  unsigned short* pBl   = (unsigned short*)alloc((size_t)H*KP*2);
  unsigned short* wihBh = (unsigned short*)alloc((size_t)3*H*KP*2);
  unsigned short* wihBl = (unsigned short*)alloc((size_t)3*H*KP*2);
  unsigned short* whhBh = (unsigned short*)alloc((size_t)3*H*KP*2);
  unsigned short* whhBl = (unsigned short*)alloc((size_t)3*H*KP*2);
  unsigned short* gBh[3]; unsigned short* gBl[3];
  for (int i = 0; i < 3; ++i) {
    gBh[i] = (unsigned short*)alloc((size_t)H*KP*2);
    gBl[i] = (unsigned short*)alloc((size_t)H*KP*2);
  }
  float* gsum  = (float*)alloc((size_t)NG*H*4);
  float* gmax  = (float*)alloc((size_t)NG*H*4);
  float* cnt   = (float*)alloc(NG*4);
  float* fc1o  = (float*)alloc((size_t)NG*H*4);
  const int NB = (NN + SCAN_B - 1) / SCAN_B;
  int* deg    = (int*)alloc((size_t)NN*4);
  int* part   = (int*)alloc((size_t)NN*4);
  int* bsum   = (int*)alloc((size_t)NB*4);
  int* rowptr = (int*)alloc((size_t)(NN+1)*4);
  int* cpos   = (int*)alloc((size_t)NN*4);
  int* elist  = (int*)alloc((size_t)NE*4);

  const int* srcp = eidx;
  const int* dstp = eidx + NE;

  // ---- CSR build (reused all 3 steps) ----
  hipMemsetAsync(deg, 0, (size_t)NN*4, stream);
  hist_k<<<(NE + 255)/256, 256, 0, stream>>>(dstp, deg);
  scan1_k<<<NB, 256, 0, stream>>>(deg, part, bsum, NN);
  scan2_k<<<1, 128, 0, stream>>>(bsum, NB);
  scan3_k<<<(NN + 255)/256, 256, 0, stream>>>(part, bsum, rowptr, cpos, NN);
  fill_k<<<(NE + 255)/256, 256, 0, stream>>>(srcp, dstp, cpos, elist);

  // ---- weight splits (zero-padded K) ----
  cvt_split<<<(int)(((long)H*KP + 255)/256), 256, 0, stream>>>(projW, pBh, pBl, H, D);
  cvt_split<<<(int)(((long)3*H*KP + 255)/256), 256, 0, stream>>>(wih, wihBh, wihBl, 3*H, H);
  cvt_split<<<(int)(((long)3*H*KP + 255)/256), 256, 0, stream>>>(whh, whhBh, whhBl, 3*H, H);
  for (int i = 0; i < 3; ++i)
    cvt_tsplit<<<(H*KP + 255)/256, 256, 0, stream>>>(ggcW + (size_t)i*H*H, gBh[i], gBl[i], H, H);

  // ---- x -> padded pitch-208 copy in bufB ----
  padx_k<<<(int)(((long)NN*LPX + 255)/256), 256, 0, stream>>>(x, bufB);

  dim3 gg((NN + 127)/128, (H + 127)/128);
  // proj + bn1 + relu : bufB(x) -> bufA(h)
  mgemm<1><<<gg, 256, 0, stream>>>(bufB, LPX, pBh, pBl, NN, H,
                                   projb, bn1g, bn1b, bn1m, bn1v, bufA);

  float* h   = bufA;
  float* m   = bufB;
  float* agg = bufC;
  for (int i = 0; i < 3; ++i) {
    mgemm<0><<<gg, 256, 0, stream>>>(h, H, gBh[i], gBl[i], NN, H,
                                     nullptr, nullptr, nullptr, nullptr, nullptr, m);
    gather_k<<<NN, 256, 0, stream>>>(m, rowptr, elist, agg);
    gru6<<<dim3((NN + 127)/128, (H + 31)/32), 256, 0, stream>>>(
        agg, h, wihBh, wihBl, whhBh, whhBl, bih, bhh, m);
    float* t = h; h = m; m = t;   // gru wrote new h into old m
  }

  hipMemsetAsync(gsum, 0, (size_t)NG*H*4, stream);
  hipMemsetAsync(gmax, 0, (size_t)NG*H*4, stream);
  pool_k<<<(int)(((long)NN*H + 255)/256), 256, 0, stream>>>(h, batch,
                                                            bn2g, bn2b, bn2m, bn2v,
                                                            gsum, gmax);
  cnt_k<<<(NG + 63)/64, 64, 0, stream>>>(batch, cnt);
  fc1_k<<<(NG*H + 255)/256, 256, 0, stream>>>(gsum, gmax, cnt, fc1W, fc1b,
                                              bnfg, bnfb, bnfm, bnfv, fc1o);
  fc2_k<<<(NG*2 + 255)/256, 256, 0, stream>>>(fc1o, fc2W, fc2b, (float*)d_out);
}

// Round 5
// 2783.373 us; speedup vs baseline: 6.9028x; 1.0048x over previous
//
#include <hip/hip_runtime.h>
#include <cmath>

#define NN 100000
#define NE 1600000
#define NG 512
#define H 200
#define D 205
#define EPSV 1e-5f
#define SCAN_B 1024
#define KP 224    // padded K extent for weight (B-side) buffers, bf16, zero-padded
#define LPX 208   // x copy pitch (fp32, 16B-multiple)

typedef __attribute__((ext_vector_type(8))) short short8v;
typedef __attribute__((ext_vector_type(4))) float f32x4;

#define MFMA16(a,b,c) __builtin_amdgcn_mfma_f32_16x16x32_bf16(a,b,c,0,0,0)

static __device__ __forceinline__ float sigm(float x){ return 1.0f/(1.0f+expf(-x)); }

// split fp32 -> bf16 hi (truncate) + bf16 lo (residual)  [identical numerics to round 4]
static __device__ __forceinline__ void split2(float x, unsigned short& h, unsigned short& l){
  unsigned xb = __float_as_uint(x);
  h = (unsigned short)(xb >> 16);
  float hf = __uint_as_float(xb & 0xffff0000u);
  l = (unsigned short)(__float_as_uint(x - hf) >> 16);
}

static __device__ __forceinline__ void splitv(float4 v0, float4 v1, short8v& hi, short8v& lo){
  float v[8] = {v0.x,v0.y,v0.z,v0.w,v1.x,v1.y,v1.z,v1.w};
  #pragma unroll
  for (int e = 0; e < 8; ++e){
    unsigned u = __float_as_uint(v[e]);
    hi[e] = (short)(u >> 16);
    float hf = __uint_as_float(u & 0xffff0000u);
    lo[e] = (short)(__float_as_uint(v[e] - hf) >> 16);
  }
}

static __device__ __forceinline__ void gload16(const void* src, void* dst){
  __builtin_amdgcn_global_load_lds(
      (const __attribute__((address_space(1))) unsigned int*)src,
      (__attribute__((address_space(3))) unsigned int*)dst, 16, 0, 0);
}

// ---------------- pad-copy x: [NN,205] fp32 -> [NN,208] fp32 ----------------
__global__ __launch_bounds__(256) void padx_k(const float* __restrict__ in, float* __restrict__ out){
  long i = (long)blockIdx.x*256 + threadIdx.x;
  if (i >= (long)NN*LPX) return;
  int r = (int)(i/LPX), c = (int)(i - (long)r*LPX);
  out[i] = (c < D) ? in[(size_t)r*D + c] : 0.f;
}

// ---------------- weight cvt: fp32 [rows,C] -> hi/lo bf16 [rows,KP], zero-padded ----------------
__global__ __launch_bounds__(256) void cvt_split(const float* __restrict__ in,
    unsigned short* __restrict__ hi, unsigned short* __restrict__ lo, int rows, int C){
  long i = (long)blockIdx.x*256 + threadIdx.x;
  long tot = (long)rows*KP;
  if (i >= tot) return;
  int r = (int)(i/KP), c = (int)(i - (long)r*KP);
  float v = (c < C) ? in[(size_t)r*C + c] : 0.f;
  unsigned short hh, ll; split2(v,hh,ll);
  hi[i] = hh; lo[i] = ll;
}

// ---------------- weight cvt + transpose: out[n][k]=in[k][n], [C,KP], zero-padded ----------------
__global__ __launch_bounds__(256) void cvt_tsplit(const float* __restrict__ in,
    unsigned short* __restrict__ hi, unsigned short* __restrict__ lo, int R, int C){
  int i = blockIdx.x*256 + threadIdx.x;
  if (i >= C*KP) return;
  int n = i/KP, k = i - n*KP;
  float v = (k < R) ? in[(size_t)k*C + n] : 0.f;
  unsigned short hh, ll; split2(v,hh,ll);
  hi[i] = hh; lo[i] = ll;
}

// ---------------- split-bf16 MFMA GEMM: C[M,N] = A(fp32) @ Bsplit^T ----------------
// grid = (N/128, M/128): j (x-dim) varies fastest -> A row-panel reused across
// adjacent blocks via L2/L3. B in LDS is granule-major: addr = q*2048 + row*16
// (2-way bank pattern on ds_read_b128 = free). Staging descriptors hoisted, divless.
template<int EPIL>
__global__ __launch_bounds__(256) void mgemm(
    const float* __restrict__ A, int LP,
    const unsigned short* __restrict__ Bhi, const unsigned short* __restrict__ Blo,
    int M, int N,
    const float* __restrict__ bias,
    const float* __restrict__ bg, const float* __restrict__ bb,
    const float* __restrict__ bm, const float* __restrict__ bv,
    float* __restrict__ C)
{
  __shared__ __align__(16) float As[128*32];              // XOR-swizzled image
  __shared__ __align__(16) unsigned short Bs[2][4096];    // [comp][q*2048B + row*16B]
  const int tid = threadIdx.x, lane = tid & 63, wave = tid >> 6;
  const int n0 = blockIdx.x*128, r0 = blockIdx.y*128;
  const int wr = (wave>>1)*64, wc = (wave&1)*64;
  const int fr = lane & 15, fq = lane >> 4;
  f32x4 acc[4][4] = {};

  // hoisted staging descriptors (k0-invariant)
  int aoff[4], adst[4];
  #pragma unroll
  for (int i = 0; i < 4; ++i) {
    int pa = wave + 4*i;                 // A chunk 0..15
    int R  = pa*8 + (lane>>3);
    int csw = (lane&7) ^ (R&7);
    int rg = r0 + R; if (rg > M-1) rg = M-1;
    aoff[i] = rg*LP + csw*4;
    adst[i] = pa*1024;
  }
  int boff[2], bdst[2];
  #pragma unroll
  for (int i = 0; i < 2; ++i) {
    int c = wave + 4*i;                  // B chunk 0..7
    int rowgrp = c>>2, q = c&3;
    int R = rowgrp*64 + lane;
    int rg = n0 + R; if (rg > N-1) rg = N-1;
    boff[i] = rg*KP + q*8;
    bdst[i] = q*2048 + rowgrp*1024;
  }

  for (int k0 = 0; k0 < KP; k0 += 32) {
    #pragma unroll
    for (int i = 0; i < 4; ++i) gload16(A + aoff[i] + k0, (char*)As + adst[i]);
    #pragma unroll
    for (int i = 0; i < 2; ++i) gload16(Bhi + boff[i] + k0, (char*)Bs[0] + bdst[i]);
    #pragma unroll
    for (int i = 0; i < 2; ++i) gload16(Blo + boff[i] + k0, (char*)Bs[1] + bdst[i]);
    __syncthreads();
    short8v ah[4], al[4], bh[4], bl[4];
    #pragma unroll
    for (int t = 0; t < 4; ++t) {
      int row = wr + t*16 + fr;
      const char* base = (const char*)As + row*128;
      int s0 = (fq*32) ^ ((row&7)<<4);
      float4 v0 = *(const float4*)(base + s0);
      float4 v1 = *(const float4*)(base + (s0 ^ 16));
      splitv(v0, v1, ah[t], al[t]);
      int rowb = wc + t*16 + fr;
      bh[t] = *(const short8v*)((const char*)Bs[0] + fq*2048 + rowb*16);
      bl[t] = *(const short8v*)((const char*)Bs[1] + fq*2048 + rowb*16);
    }
    #pragma unroll
    for (int i = 0; i < 4; ++i)
      #pragma unroll
      for (int j = 0; j < 4; ++j) {
        acc[i][j] = MFMA16(ah[i], bh[j], acc[i][j]);
        acc[i][j] = MFMA16(ah[i], bl[j], acc[i][j]);
        acc[i][j] = MFMA16(al[i], bh[j], acc[i][j]);
      }
    __syncthreads();
  }

  #pragma unroll
  for (int i = 0; i < 4; ++i)
    #pragma unroll
    for (int j = 0; j < 4; ++j)
      #pragma unroll
      for (int q = 0; q < 4; ++q) {
        int row = r0 + wr + i*16 + fq*4 + q;
        int col = n0 + wc + j*16 + fr;
        if (row < M && col < N) {
          float c = acc[i][j][q];
          if (EPIL) {
            c += bias[col];
            c = (c - bm[col]) * (bg[col] * rsqrtf(bv[col] + EPSV)) + bb[col];
            c = fmaxf(c, 0.f);
          }
          C[(size_t)row*N + col] = c;
        }
      }
}

// ---------------- fused GRU: 6 gate-GEMMs (MFMA) + elementwise ----------------
// grid = (7 j-tiles, 782 row-panels): j fastest -> agg/h row-panel L2/L3 reuse.
// Ws granule-major: comp region 12KB, addr = q*3072 + row*16 (2-way, free).
__global__ __launch_bounds__(256) void gru6(
    const float* __restrict__ agg, const float* __restrict__ hprev,
    const unsigned short* __restrict__ Wihh, const unsigned short* __restrict__ Wihl, // [600,KP]
    const unsigned short* __restrict__ Whhh, const unsigned short* __restrict__ Whhl,
    const float* __restrict__ bih, const float* __restrict__ bhh,
    float* __restrict__ hnew)
{
  __shared__ __align__(16) float Gs[128*32];
  __shared__ __align__(16) float Hs[128*32];
  __shared__ __align__(16) unsigned short Ws[2][6144];   // [comp][q*3072B + row*16B], rows 0..191
  const int tid = threadIdx.x, lane = tid & 63, wave = tid >> 6;
  const int j0 = blockIdx.x*32, r0 = blockIdx.y*128;
  const int fr = lane & 15, fq = lane >> 4;
  f32x4 acc[6][2][2] = {};   // [gate][row-sub][col-sub]

  // hoisted staging descriptors
  int aoff[4], adst[4];
  #pragma unroll
  for (int i = 0; i < 4; ++i) {
    int pa = wave + 4*i;                 // chunk 0..15 (same geometry for Gs and Hs)
    int R  = pa*8 + (lane>>3);
    int csw = (lane&7) ^ (R&7);
    int rg = r0 + R; if (rg > NN-1) rg = NN-1;
    aoff[i] = rg*H + csw*4;
    adst[i] = pa*1024;
  }
  int woff[3], wdst[3];
  const unsigned short* sph[3];
  const unsigned short* spl[3];
  #pragma unroll
  for (int i = 0; i < 3; ++i) {
    int c = wave + 4*i;                  // W chunk 0..11
    int rowgrp = c>>2, q = c&3;
    int R = rowgrp*64 + lane;            // 0..191 = gate*32 + jj
    int gate = R>>5, jj = R&31;
    int g3 = (gate >= 3) ? gate-3 : gate;
    int jcol = j0 + jj; if (jcol > H-1) jcol = H-1;
    woff[i] = (g3*H + jcol)*KP + q*8;
    wdst[i] = q*3072 + rowgrp*1024;
    sph[i] = (gate < 3) ? Wihh : Whhh;
    spl[i] = (gate < 3) ? Wihl : Whhl;
  }

  for (int k0 = 0; k0 < KP; k0 += 32) {
    #pragma unroll
    for (int i = 0; i < 4; ++i) gload16(agg   + aoff[i] + k0, (char*)Gs + adst[i]);
    #pragma unroll
    for (int i = 0; i < 4; ++i) gload16(hprev + aoff[i] + k0, (char*)Hs + adst[i]);
    #pragma unroll
    for (int i = 0; i < 3; ++i) gload16(sph[i] + woff[i] + k0, (char*)Ws[0] + wdst[i]);
    #pragma unroll
    for (int i = 0; i < 3; ++i) gload16(spl[i] + woff[i] + k0, (char*)Ws[1] + wdst[i]);
    __syncthreads();
    short8v gh[2], gl[2], hh[2], hl[2];
    #pragma unroll
    for (int t = 0; t < 2; ++t) {
      int row = wave*32 + t*16 + fr;
      int s0 = (fq*32) ^ ((row&7)<<4);
      const char* gb = (const char*)Gs + row*128;
      const char* hb = (const char*)Hs + row*128;
      splitv(*(const float4*)(gb+s0), *(const float4*)(gb+(s0^16)), gh[t], gl[t]);
      splitv(*(const float4*)(hb+s0), *(const float4*)(hb+(s0^16)), hh[t], hl[t]);
    }
    #pragma unroll
    for (int g = 0; g < 6; ++g) {
      const char* w0 = (const char*)Ws[0] + fq*3072;
      const char* w1 = (const char*)Ws[1] + fq*3072;
      short8v b0h = *(const short8v*)(w0 + (g*32      + fr)*16);
      short8v b1h = *(const short8v*)(w0 + (g*32 + 16 + fr)*16);
      short8v b0l = *(const short8v*)(w1 + (g*32      + fr)*16);
      short8v b1l = *(const short8v*)(w1 + (g*32 + 16 + fr)*16);
      #pragma unroll
      for (int t = 0; t < 2; ++t) {
        short8v a_h = (g < 3) ? gh[t] : hh[t];
        short8v a_l = (g < 3) ? gl[t] : hl[t];
        acc[g][t][0] = MFMA16(a_h, b0h, acc[g][t][0]);
        acc[g][t][0] = MFMA16(a_h, b0l, acc[g][t][0]);
        acc[g][t][0] = MFMA16(a_l, b0h, acc[g][t][0]);
        acc[g][t][1] = MFMA16(a_h, b1h, acc[g][t][1]);
        acc[g][t][1] = MFMA16(a_h, b1l, acc[g][t][1]);
        acc[g][t][1] = MFMA16(a_l, b1h, acc[g][t][1]);
      }
    }
    __syncthreads();
  }

  #pragma unroll
  for (int ct = 0; ct < 2; ++ct) {
    int j = j0 + ct*16 + fr;
    if (j >= H) continue;
    float br  = bih[j]     + bhh[j];
    float bz  = bih[H+j]   + bhh[H+j];
    float bin = bih[2*H+j], bhn = bhh[2*H+j];
    #pragma unroll
    for (int t = 0; t < 2; ++t)
      #pragma unroll
      for (int q = 0; q < 4; ++q) {
        int row = r0 + wave*32 + t*16 + fq*4 + q;
        if (row >= NN) continue;
        float ir = acc[0][t][ct][q], iz = acc[1][t][ct][q], inn = acc[2][t][ct][q];
        float hr = acc[3][t][ct][q], hz = acc[4][t][ct][q], hn  = acc[5][t][ct][q];
        float r = sigm(ir + hr + br);
        float z = sigm(iz + hz + bz);
        float n = tanhf(inn + bin + r*(hn + bhn));
        size_t o = (size_t)row*H + j;
        float ho = hprev[o];
        hnew[o] = (1.f - z)*n + z*ho;
      }
  }
}

// ---------------- CSR build ----------------
__global__ __launch_bounds__(256) void hist_k(const int* __restrict__ dst, int* __restrict__ deg){
  int e = blockIdx.x*256 + threadIdx.x;
  if (e < NE) atomicAdd(&deg[dst[e]], 1);
}

__global__ __launch_bounds__(256) void scan1_k(const int* __restrict__ deg, int* __restrict__ part,
                                               int* __restrict__ bsum, int n){
  __shared__ int lds[256];
  int t = threadIdx.x;
  int base = blockIdx.x * SCAN_B + t*4;
  int v[4]; int s = 0;
  #pragma unroll
  for (int q = 0; q < 4; ++q){ int idx = base+q; v[q] = (idx < n) ? deg[idx] : 0; s += v[q]; }
  lds[t] = s;
  __syncthreads();
  for (int off = 1; off < 256; off <<= 1){
    int val = 0;
    if (t >= off) val = lds[t-off];
    __syncthreads();
    if (t >= off) lds[t] += val;
    __syncthreads();
  }
  if (t == 255) bsum[blockIdx.x] = lds[255];
  int run = (t == 0) ? 0 : lds[t-1];
  #pragma unroll
  for (int q = 0; q < 4; ++q){ int idx = base+q; if (idx < n) part[idx] = run; run += v[q]; }
}

__global__ void scan2_k(int* __restrict__ bsum, int nb){
  __shared__ int lds[128];
  int t = threadIdx.x;
  int v = (t < nb) ? bsum[t] : 0;
  lds[t] = v;
  __syncthreads();
  for (int off = 1; off < 128; off <<= 1){
    int val = 0;
    if (t >= off) val = lds[t-off];
    __syncthreads();
    if (t >= off) lds[t] += val;
    __syncthreads();
  }
  if (t < nb) bsum[t] = (t == 0) ? 0 : lds[t-1];
}

__global__ __launch_bounds__(256) void scan3_k(const int* __restrict__ part, const int* __restrict__ bsum,
                                               int* __restrict__ rowptr, int* __restrict__ cpos, int n){
  int i = blockIdx.x*256 + threadIdx.x;
  if (i < n){
    int v = part[i] + bsum[i >> 10];
    rowptr[i] = v;
    cpos[i] = v;
  }
  if (i == 0) rowptr[n] = NE;
}

__global__ __launch_bounds__(256) void fill_k(const int* __restrict__ src, const int* __restrict__ dst,
                                              int* __restrict__ cpos, int* __restrict__ elist){
  int e = blockIdx.x*256 + threadIdx.x;
  if (e < NE){
    int p = atomicAdd(&cpos[dst[e]], 1);
    elist[p] = src[e];
  }
}

// ---------------- gather: agg[n] = sum over in-edges of m[src] (fp32) ----------------
__global__ __launch_bounds__(256) void gather_k(const float* __restrict__ m,
                                                const int* __restrict__ rowptr,
                                                const int* __restrict__ elist,
                                                float* __restrict__ agg){
  int n = blockIdx.x;
  int beg = rowptr[n], end = rowptr[n+1];
  int j = threadIdx.x;
  float acc = 0.f;
  if (j < H)
    for (int k = beg; k < end; ++k){
      int s = elist[k];
      acc += m[(size_t)s*H + j];
    }
  if (j < H) agg[(size_t)n*H + j] = acc;
}

// ---------------- pooling ----------------
__global__ __launch_bounds__(256) void pool_k(
    const float* __restrict__ h, const int* __restrict__ batch,
    const float* __restrict__ g2, const float* __restrict__ b2,
    const float* __restrict__ m2, const float* __restrict__ v2,
    float* __restrict__ gsum, float* __restrict__ gmax)
{
  long tid = (long)blockIdx.x*256 + threadIdx.x;
  if (tid >= (long)NN*H) return;
  int n = (int)(tid / H), j = (int)(tid - (long)n*H);
  float s = g2[j] * rsqrtf(v2[j] + EPSV);
  float val = (h[tid] - m2[j]) * s + b2[j];
  val = fmaxf(val, 0.f);
  int b = batch[n];
  unsafeAtomicAdd(&gsum[b*H + j], val);
  atomicMax((int*)&gmax[b*H + j], __float_as_int(val));
}

__global__ void cnt_k(const int* __restrict__ batch, float* __restrict__ cnt){
  int g = blockIdx.x*64 + threadIdx.x;
  if (g >= NG) return;
  int lo = 0, hi = NN;
  while (lo < hi){ int mid = (lo+hi)>>1; if (batch[mid] < g) lo = mid+1; else hi = mid; }
  int lo2 = lo, hi2 = NN;
  while (lo2 < hi2){ int mid = (lo2+hi2)>>1; if (batch[mid] < g+1) lo2 = mid+1; else hi2 = mid; }
  cnt[g] = (float)(lo2 - lo);
}

__global__ __launch_bounds__(256) void fc1_k(
    const float* __restrict__ gsum, const float* __restrict__ gmax,
    const float* __restrict__ cnt, const float* __restrict__ W,
    const float* __restrict__ bias,
    const float* __restrict__ fg, const float* __restrict__ fb,
    const float* __restrict__ fm, const float* __restrict__ fv,
    float* __restrict__ out)
{
  int tid = blockIdx.x*256 + threadIdx.x;
  if (tid >= NG*H) return;
  int g = tid / H, j = tid - g*H;
  float inv = 1.f / fmaxf(cnt[g], 1.f);
  const float* wr = W + j*2*H;
  float acc = bias[j];
  for (int k = 0; k < H; ++k) acc += gsum[g*H + k]*inv * wr[k];
  for (int k = 0; k < H; ++k) acc += gmax[g*H + k] * wr[H + k];
  float s = fg[j] * rsqrtf(fv[j] + EPSV);
  acc = (acc - fm[j]) * s + fb[j];
  out[tid] = fmaxf(acc, 0.f);
}

__global__ void fc2_k(const float* __restrict__ in, const float* __restrict__ W,
                      const float* __restrict__ bias, float* __restrict__ out)
{
  int tid = blockIdx.x*256 + threadIdx.x;
  if (tid >= NG*2) return;
  int g = tid >> 1, c = tid & 1;
  float acc = bias[c];
  const float* wr = W + c*H;
  const float* xr = in + g*H;
  for (int k = 0; k < H; ++k) acc += xr[k]*wr[k];
  out[tid] = acc;
}

extern "C" void kernel_launch(void* const* d_in, const int* in_sizes, int n_in,
                              void* d_out, int out_size, void* d_ws, size_t ws_size,
                              hipStream_t stream)
{
  const float* x     = (const float*)d_in[0];
  const int*   eidx  = (const int*)d_in[1];
  const int*   batch = (const int*)d_in[2];
  const float* projW = (const float*)d_in[3];
  const float* projb = (const float*)d_in[4];
  const float* bn1g  = (const float*)d_in[5];
  const float* bn1b  = (const float*)d_in[6];
  const float* bn1m  = (const float*)d_in[7];
  const float* bn1v  = (const float*)d_in[8];
  const float* bn2g  = (const float*)d_in[9];
  const float* bn2b  = (const float*)d_in[10];
  const float* bn2m  = (const float*)d_in[11];
  const float* bn2v  = (const float*)d_in[12];
  const float* bnfg  = (const float*)d_in[13];
  const float* bnfb  = (const float*)d_in[14];
  const float* bnfm  = (const float*)d_in[15];
  const float* bnfv  = (const float*)d_in[16];
  const float* ggcW  = (const float*)d_in[17];
  const float* wih   = (const float*)d_in[18];
  const float* whh   = (const float*)d_in[19];
  const float* bih   = (const float*)d_in[20];
  const float* bhh   = (const float*)d_in[21];
  const float* fc1W  = (const float*)d_in[22];
  const float* fc1b  = (const float*)d_in[23];
  const float* fc2W  = (const float*)d_in[24];
  const float* fc2b  = (const float*)d_in[25];

  char* wsp = (char*)d_ws;
  auto alloc = [&](size_t nbytes) {
    char* p = wsp;
    wsp += ((nbytes + 255) / 256) * 256;
    return (void*)p;
  };
  // three rotating fp32 node buffers (bufB oversized for the 208-pitch x copy)
  float* bufA = (float*)alloc((size_t)NN*H*4);
  float* bufB = (float*)alloc((size_t)NN*LPX*4);
  float* bufC = (float*)alloc((size_t)NN*H*4);
  // weights (bf16 split, zero-padded to KP)
  unsigned short* pBh   = (unsigned short*)alloc((size_t)H*KP*2);
  unsigned short* pBl   = (unsigned short*)alloc((size_t)H*KP*2);
  unsigned short* wihBh = (unsigned short*)alloc((size_t)3*H*KP*2);
  unsigned short* wihBl = (unsigned short*)alloc((size_t)3*H*KP*2);
  unsigned short* whhBh = (unsigned short*)alloc((size_t)3*H*KP*2);
  unsigned short* whhBl = (unsigned short*)alloc((size_t)3*H*KP*2);
  unsigned short* gBh[3]; unsigned short* gBl[3];
  for (int i = 0; i < 3; ++i) {
    gBh[i] = (unsigned short*)alloc((size_t)H*KP*2);
    gBl[i] = (unsigned short*)alloc((size_t)H*KP*2);
  }
  float* gsum  = (float*)alloc((size_t)NG*H*4);
  float* gmax  = (float*)alloc((size_t)NG*H*4);
  float* cnt   = (float*)alloc(NG*4);
  float* fc1o  = (float*)alloc((size_t)NG*H*4);
  const int NB = (NN + SCAN_B - 1) / SCAN_B;
  int* deg    = (int*)alloc((size_t)NN*4);
  int* part   = (int*)alloc((size_t)NN*4);
  int* bsum   = (int*)alloc((size_t)NB*4);
  int* rowptr = (int*)alloc((size_t)(NN+1)*4);
  int* cpos   = (int*)alloc((size_t)NN*4);
  int* elist  = (int*)alloc((size_t)NE*4);

  const int* srcp = eidx;
  const int* dstp = eidx + NE;

  // ---- CSR build (reused all 3 steps) ----
  hipMemsetAsync(deg, 0, (size_t)NN*4, stream);
  hist_k<<<(NE + 255)/256, 256, 0, stream>>>(dstp, deg);
  scan1_k<<<NB, 256, 0, stream>>>(deg, part, bsum, NN);
  scan2_k<<<1, 128, 0, stream>>>(bsum, NB);
  scan3_k<<<(NN + 255)/256, 256, 0, stream>>>(part, bsum, rowptr, cpos, NN);
  fill_k<<<(NE + 255)/256, 256, 0, stream>>>(srcp, dstp, cpos, elist);

  // ---- weight splits (zero-padded K) ----
  cvt_split<<<(int)(((long)H*KP + 255)/256), 256, 0, stream>>>(projW, pBh, pBl, H, D);
  cvt_split<<<(int)(((long)3*H*KP + 255)/256), 256, 0, stream>>>(wih, wihBh, wihBl, 3*H, H);
  cvt_split<<<(int)(((long)3*H*KP + 255)/256), 256, 0, stream>>>(whh, whhBh, whhBl, 3*H, H);
  for (int i = 0; i < 3; ++i)
    cvt_tsplit<<<(H*KP + 255)/256, 256, 0, stream>>>(ggcW + (size_t)i*H*H, gBh[i], gBl[i], H, H);

  // ---- x -> padded pitch-208 copy in bufB ----
  padx_k<<<(int)(((long)NN*LPX + 255)/256), 256, 0, stream>>>(x, bufB);

  dim3 gg((H + 127)/128, (NN + 127)/128);   // j fastest
  // proj + bn1 + relu : bufB(x) -> bufA(h)
  mgemm<1><<<gg, 256, 0, stream>>>(bufB, LPX, pBh, pBl, NN, H,
                                   projb, bn1g, bn1b, bn1m, bn1v, bufA);

  float* h   = bufA;
  float* m   = bufB;
  float* agg = bufC;
  for (int i = 0; i < 3; ++i) {
    mgemm<0><<<gg, 256, 0, stream>>>(h, H, gBh[i], gBl[i], NN, H,
                                     nullptr, nullptr, nullptr, nullptr, nullptr, m);
    gather_k<<<NN, 256, 0, stream>>>(m, rowptr, elist, agg);
    gru6<<<dim3((H + 31)/32, (NN + 127)/128), 256, 0, stream>>>(
        agg, h, wihBh, wihBl, whhBh, whhBl, bih, bhh, m);
    float* t = h; h = m; m = t;   // gru wrote new h into old m
  }

  hipMemsetAsync(gsum, 0, (size_t)NG*H*4, stream);
  hipMemsetAsync(gmax, 0, (size_t)NG*H*4, stream);
  pool_k<<<(int)(((long)NN*H + 255)/256), 256, 0, stream>>>(h, batch,
                                                            bn2g, bn2b, bn2m, bn2v,
                                                            gsum, gmax);
  cnt_k<<<(NG + 63)/64, 64, 0, stream>>>(batch, cnt);
  fc1_k<<<(NG*H + 255)/256, 256, 0, stream>>>(gsum, gmax, cnt, fc1W, fc1b,
                                              bnfg, bnfb, bnfm, bnfv, fc1o);
  fc2_k<<<(NG*2 + 255)/256, 256, 0, stream>>>(fc1o, fc2W, fc2b, (float*)d_out);
}

// Round 6
// 2343.656 us; speedup vs baseline: 8.1979x; 1.1876x over previous
//
#include <hip/hip_runtime.h>
#include <cmath>

#define NN 100000
#define NE 1600000
#define NG 512
#define H 200
#define D 205
#define EPSV 1e-5f
#define SCAN_B 1024
#define KP 224    // padded K extent for weight (B-side) buffers, bf16, zero-padded
#define LPX 208   // x copy pitch (fp32, 16B-multiple)

typedef __attribute__((ext_vector_type(8))) short short8v;
typedef __attribute__((ext_vector_type(4))) float f32x4;

#define MFMA16(a,b,c) __builtin_amdgcn_mfma_f32_16x16x32_bf16(a,b,c,0,0,0)

static __device__ __forceinline__ float sigm(float x){ return 1.0f/(1.0f+expf(-x)); }

// split fp32 -> bf16 hi (truncate) + bf16 lo (residual)
static __device__ __forceinline__ void split2(float x, unsigned short& h, unsigned short& l){
  unsigned xb = __float_as_uint(x);
  h = (unsigned short)(xb >> 16);
  float hf = __uint_as_float(xb & 0xffff0000u);
  l = (unsigned short)(__float_as_uint(x - hf) >> 16);
}

static __device__ __forceinline__ void splitv(float4 v0, float4 v1, short8v& hi, short8v& lo){
  float v[8] = {v0.x,v0.y,v0.z,v0.w,v1.x,v1.y,v1.z,v1.w};
  #pragma unroll
  for (int e = 0; e < 8; ++e){
    unsigned u = __float_as_uint(v[e]);
    hi[e] = (short)(u >> 16);
    float hf = __uint_as_float(u & 0xffff0000u);
    lo[e] = (short)(__float_as_uint(v[e] - hf) >> 16);
  }
}

static __device__ __forceinline__ void gload16(const void* src, void* dst){
  __builtin_amdgcn_global_load_lds(
      (const __attribute__((address_space(1))) unsigned int*)src,
      (__attribute__((address_space(3))) unsigned int*)dst, 16, 0, 0);
}

// ---------------- pad-copy x: [NN,205] fp32 -> [NN,208] fp32 ----------------
__global__ __launch_bounds__(256) void padx_k(const float* __restrict__ in, float* __restrict__ out){
  long i = (long)blockIdx.x*256 + threadIdx.x;
  if (i >= (long)NN*LPX) return;
  int r = (int)(i/LPX), c = (int)(i - (long)r*LPX);
  out[i] = (c < D) ? in[(size_t)r*D + c] : 0.f;
}

// ---------------- weight cvt: fp32 [rows,C] -> hi/lo bf16 [rows,KP], zero-padded ----------------
__global__ __launch_bounds__(256) void cvt_split(const float* __restrict__ in,
    unsigned short* __restrict__ hi, unsigned short* __restrict__ lo, int rows, int C){
  long i = (long)blockIdx.x*256 + threadIdx.x;
  long tot = (long)rows*KP;
  if (i >= tot) return;
  int r = (int)(i/KP), c = (int)(i - (long)r*KP);
  float v = (c < C) ? in[(size_t)r*C + c] : 0.f;
  unsigned short hh, ll; split2(v,hh,ll);
  hi[i] = hh; lo[i] = ll;
}

// ---------------- weight cvt + transpose: out[n][k]=in[k][n], [C,KP], zero-padded ----------------
__global__ __launch_bounds__(256) void cvt_tsplit(const float* __restrict__ in,
    unsigned short* __restrict__ hi, unsigned short* __restrict__ lo, int R, int C){
  int i = blockIdx.x*256 + threadIdx.x;
  if (i >= C*KP) return;
  int n = i/KP, k = i - n*KP;
  float v = (k < R) ? in[(size_t)k*C + n] : 0.f;
  unsigned short hh, ll; split2(v,hh,ll);
  hi[i] = hh; lo[i] = ll;
}

// ---------------- split-bf16 MFMA GEMM: C[M,N] = A(fp32) @ Bsplit^T ----------------
// XCD-grouped 1-D grid: all nj j-tiles of a row-panel run on ONE XCD at
// consecutive slots -> panel fetched from HBM once, re-reads hit that XCD's L2.
// Decode (HW: xcd = bid & 7): s=bid>>3; panel = (s/nj)*8 + (bid&7); j = s%nj.
template<int EPIL>
__global__ __launch_bounds__(256) void mgemm(
    const float* __restrict__ A, int LP,
    const unsigned short* __restrict__ Bhi, const unsigned short* __restrict__ Blo,
    int M, int N, int nj, int npan,
    const float* __restrict__ bias,
    const float* __restrict__ bg, const float* __restrict__ bb,
    const float* __restrict__ bm, const float* __restrict__ bv,
    float* __restrict__ C)
{
  __shared__ __align__(16) float As[128*32];              // XOR-swizzled image
  __shared__ __align__(16) unsigned short Bs[2][4096];    // [comp][q*2048B + row*16B]
  const int bid = blockIdx.x;
  const int xcd = bid & 7, s = bid >> 3;
  const int pl = s / nj, jj = s - pl*nj;
  const int p = pl*8 + xcd;
  if (p >= npan) return;
  const int n0 = jj*128, r0 = p*128;
  const int tid = threadIdx.x, lane = tid & 63, wave = tid >> 6;
  const int wr = (wave>>1)*64, wc = (wave&1)*64;
  const int fr = lane & 15, fq = lane >> 4;
  f32x4 acc[4][4] = {};

  // hoisted staging descriptors (k0-invariant)
  int aoff[4], adst[4];
  #pragma unroll
  for (int i = 0; i < 4; ++i) {
    int pa = wave + 4*i;                 // A chunk 0..15
    int R  = pa*8 + (lane>>3);
    int csw = (lane&7) ^ (R&7);
    int rg = r0 + R; if (rg > M-1) rg = M-1;
    aoff[i] = rg*LP + csw*4;
    adst[i] = pa*1024;
  }
  int boff[2], bdst[2];
  #pragma unroll
  for (int i = 0; i < 2; ++i) {
    int c = wave + 4*i;                  // B chunk 0..7
    int rowgrp = c>>2, q = c&3;
    int R = rowgrp*64 + lane;
    int rg = n0 + R; if (rg > N-1) rg = N-1;
    boff[i] = rg*KP + q*8;
    bdst[i] = q*2048 + rowgrp*1024;
  }

  for (int k0 = 0; k0 < KP; k0 += 32) {
    #pragma unroll
    for (int i = 0; i < 4; ++i) gload16(A + aoff[i] + k0, (char*)As + adst[i]);
    #pragma unroll
    for (int i = 0; i < 2; ++i) gload16(Bhi + boff[i] + k0, (char*)Bs[0] + bdst[i]);
    #pragma unroll
    for (int i = 0; i < 2; ++i) gload16(Blo + boff[i] + k0, (char*)Bs[1] + bdst[i]);
    __syncthreads();
    short8v ah[4], al[4], bh[4], bl[4];
    #pragma unroll
    for (int t = 0; t < 4; ++t) {
      int row = wr + t*16 + fr;
      const char* base = (const char*)As + row*128;
      int s0 = (fq*32) ^ ((row&7)<<4);
      float4 v0 = *(const float4*)(base + s0);
      float4 v1 = *(const float4*)(base + (s0 ^ 16));
      splitv(v0, v1, ah[t], al[t]);
      int rowb = wc + t*16 + fr;
      bh[t] = *(const short8v*)((const char*)Bs[0] + fq*2048 + rowb*16);
      bl[t] = *(const short8v*)((const char*)Bs[1] + fq*2048 + rowb*16);
    }
    #pragma unroll
    for (int i = 0; i < 4; ++i)
      #pragma unroll
      for (int j = 0; j < 4; ++j) {
        acc[i][j] = MFMA16(ah[i], bh[j], acc[i][j]);
        acc[i][j] = MFMA16(ah[i], bl[j], acc[i][j]);
        acc[i][j] = MFMA16(al[i], bh[j], acc[i][j]);
      }
    __syncthreads();
  }

  #pragma unroll
  for (int i = 0; i < 4; ++i)
    #pragma unroll
    for (int j = 0; j < 4; ++j)
      #pragma unroll
      for (int q = 0; q < 4; ++q) {
        int row = r0 + wr + i*16 + fq*4 + q;
        int col = n0 + wc + j*16 + fr;
        if (row < M && col < N) {
          float c = acc[i][j][q];
          if (EPIL) {
            c += bias[col];
            c = (c - bm[col]) * (bg[col] * rsqrtf(bv[col] + EPSV)) + bb[col];
            c = fmaxf(c, 0.f);
          }
          C[(size_t)row*N + col] = c;
        }
      }
}

// ---------------- fused GRU: 6 gate-GEMMs (MFMA) + elementwise ----------------
// XCD-grouped grid, nj=7 j-tiles per 128-row panel on one XCD.
__global__ __launch_bounds__(256) void gru6(
    const float* __restrict__ agg, const float* __restrict__ hprev,
    const unsigned short* __restrict__ Wihh, const unsigned short* __restrict__ Wihl, // [600,KP]
    const unsigned short* __restrict__ Whhh, const unsigned short* __restrict__ Whhl,
    const float* __restrict__ bih, const float* __restrict__ bhh,
    int nj, int npan,
    float* __restrict__ hnew)
{
  __shared__ __align__(16) float Gs[128*32];
  __shared__ __align__(16) float Hs[128*32];
  __shared__ __align__(16) unsigned short Ws[2][6144];   // [comp][q*3072B + row*16B]
  const int bid = blockIdx.x;
  const int xcd = bid & 7, sl = bid >> 3;
  const int pl = sl / nj, jt = sl - pl*nj;
  const int p = pl*8 + xcd;
  if (p >= npan) return;
  const int j0 = jt*32, r0 = p*128;
  const int tid = threadIdx.x, lane = tid & 63, wave = tid >> 6;
  const int fr = lane & 15, fq = lane >> 4;
  f32x4 acc[6][2][2] = {};   // [gate][row-sub][col-sub]

  // hoisted staging descriptors
  int aoff[4], adst[4];
  #pragma unroll
  for (int i = 0; i < 4; ++i) {
    int pa = wave + 4*i;                 // chunk 0..15 (same geometry for Gs and Hs)
    int R  = pa*8 + (lane>>3);
    int csw = (lane&7) ^ (R&7);
    int rg = r0 + R; if (rg > NN-1) rg = NN-1;
    aoff[i] = rg*H + csw*4;
    adst[i] = pa*1024;
  }
  int woff[3], wdst[3];
  const unsigned short* sph[3];
  const unsigned short* spl[3];
  #pragma unroll
  for (int i = 0; i < 3; ++i) {
    int c = wave + 4*i;                  // W chunk 0..11
    int rowgrp = c>>2, q = c&3;
    int R = rowgrp*64 + lane;            // 0..191 = gate*32 + jj
    int gate = R>>5, jj = R&31;
    int g3 = (gate >= 3) ? gate-3 : gate;
    int jcol = j0 + jj; if (jcol > H-1) jcol = H-1;
    woff[i] = (g3*H + jcol)*KP + q*8;
    wdst[i] = q*3072 + rowgrp*1024;
    sph[i] = (gate < 3) ? Wihh : Whhh;
    spl[i] = (gate < 3) ? Wihl : Whhl;
  }

  for (int k0 = 0; k0 < KP; k0 += 32) {
    #pragma unroll
    for (int i = 0; i < 4; ++i) gload16(agg   + aoff[i] + k0, (char*)Gs + adst[i]);
    #pragma unroll
    for (int i = 0; i < 4; ++i) gload16(hprev + aoff[i] + k0, (char*)Hs + adst[i]);
    #pragma unroll
    for (int i = 0; i < 3; ++i) gload16(sph[i] + woff[i] + k0, (char*)Ws[0] + wdst[i]);
    #pragma unroll
    for (int i = 0; i < 3; ++i) gload16(spl[i] + woff[i] + k0, (char*)Ws[1] + wdst[i]);
    __syncthreads();
    short8v gh[2], gl[2], hh[2], hl[2];
    #pragma unroll
    for (int t = 0; t < 2; ++t) {
      int row = wave*32 + t*16 + fr;
      int s0 = (fq*32) ^ ((row&7)<<4);
      const char* gb = (const char*)Gs + row*128;
      const char* hb = (const char*)Hs + row*128;
      splitv(*(const float4*)(gb+s0), *(const float4*)(gb+(s0^16)), gh[t], gl[t]);
      splitv(*(const float4*)(hb+s0), *(const float4*)(hb+(s0^16)), hh[t], hl[t]);
    }
    #pragma unroll
    for (int g = 0; g < 6; ++g) {
      const char* w0 = (const char*)Ws[0] + fq*3072;
      const char* w1 = (const char*)Ws[1] + fq*3072;
      short8v b0h = *(const short8v*)(w0 + (g*32      + fr)*16);
      short8v b1h = *(const short8v*)(w0 + (g*32 + 16 + fr)*16);
      short8v b0l = *(const short8v*)(w1 + (g*32      + fr)*16);
      short8v b1l = *(const short8v*)(w1 + (g*32 + 16 + fr)*16);
      #pragma unroll
      for (int t = 0; t < 2; ++t) {
        short8v a_h = (g < 3) ? gh[t] : hh[t];
        short8v a_l = (g < 3) ? gl[t] : hl[t];
        acc[g][t][0] = MFMA16(a_h, b0h, acc[g][t][0]);
        acc[g][t][0] = MFMA16(a_h, b0l, acc[g][t][0]);
        acc[g][t][0] = MFMA16(a_l, b0h, acc[g][t][0]);
        acc[g][t][1] = MFMA16(a_h, b1h, acc[g][t][1]);
        acc[g][t][1] = MFMA16(a_h, b1l, acc[g][t][1]);
        acc[g][t][1] = MFMA16(a_l, b1h, acc[g][t][1]);
      }
    }
    __syncthreads();
  }

  #pragma unroll
  for (int ct = 0; ct < 2; ++ct) {
    int j = j0 + ct*16 + fr;
    if (j >= H) continue;
    float br  = bih[j]     + bhh[j];
    float bz  = bih[H+j]   + bhh[H+j];
    float bin = bih[2*H+j], bhn = bhh[2*H+j];
    #pragma unroll
    for (int t = 0; t < 2; ++t)
      #pragma unroll
      for (int q = 0; q < 4; ++q) {
        int row = r0 + wave*32 + t*16 + fq*4 + q;
        if (row >= NN) continue;
        float ir = acc[0][t][ct][q], iz = acc[1][t][ct][q], inn = acc[2][t][ct][q];
        float hr = acc[3][t][ct][q], hz = acc[4][t][ct][q], hn  = acc[5][t][ct][q];
        float r = sigm(ir + hr + br);
        float z = sigm(iz + hz + bz);
        float n = tanhf(inn + bin + r*(hn + bhn));
        size_t o = (size_t)row*H + j;
        float ho = hprev[o];
        hnew[o] = (1.f - z)*n + z*ho;
      }
  }
}

// ---------------- CSR build ----------------
__global__ __launch_bounds__(256) void hist_k(const int* __restrict__ dst, int* __restrict__ deg){
  int e = blockIdx.x*256 + threadIdx.x;
  if (e < NE) atomicAdd(&deg[dst[e]], 1);
}

__global__ __launch_bounds__(256) void scan1_k(const int* __restrict__ deg, int* __restrict__ part,
                                               int* __restrict__ bsum, int n){
  __shared__ int lds[256];
  int t = threadIdx.x;
  int base = blockIdx.x * SCAN_B + t*4;
  int v[4]; int s = 0;
  #pragma unroll
  for (int q = 0; q < 4; ++q){ int idx = base+q; v[q] = (idx < n) ? deg[idx] : 0; s += v[q]; }
  lds[t] = s;
  __syncthreads();
  for (int off = 1; off < 256; off <<= 1){
    int val = 0;
    if (t >= off) val = lds[t-off];
    __syncthreads();
    if (t >= off) lds[t] += val;
    __syncthreads();
  }
  if (t == 255) bsum[blockIdx.x] = lds[255];
  int run = (t == 0) ? 0 : lds[t-1];
  #pragma unroll
  for (int q = 0; q < 4; ++q){ int idx = base+q; if (idx < n) part[idx] = run; run += v[q]; }
}

__global__ void scan2_k(int* __restrict__ bsum, int nb){
  __shared__ int lds[128];
  int t = threadIdx.x;
  int v = (t < nb) ? bsum[t] : 0;
  lds[t] = v;
  __syncthreads();
  for (int off = 1; off < 128; off <<= 1){
    int val = 0;
    if (t >= off) val = lds[t-off];
    __syncthreads();
    if (t >= off) lds[t] += val;
    __syncthreads();
  }
  if (t < nb) bsum[t] = (t == 0) ? 0 : lds[t-1];
}

__global__ __launch_bounds__(256) void scan3_k(const int* __restrict__ part, const int* __restrict__ bsum,
                                               int* __restrict__ rowptr, int* __restrict__ cpos, int n){
  int i = blockIdx.x*256 + threadIdx.x;
  if (i < n){
    int v = part[i] + bsum[i >> 10];
    rowptr[i] = v;
    cpos[i] = v;
  }
  if (i == 0) rowptr[n] = NE;
}

__global__ __launch_bounds__(256) void fill_k(const int* __restrict__ src, const int* __restrict__ dst,
                                              int* __restrict__ cpos, int* __restrict__ elist){
  int e = blockIdx.x*256 + threadIdx.x;
  if (e < NE){
    int p = atomicAdd(&cpos[dst[e]], 1);
    elist[p] = src[e];
  }
}

// ---------------- gather: agg[n] = sum over in-edges of m[src] (fp32) ----------------
__global__ __launch_bounds__(256) void gather_k(const float* __restrict__ m,
                                                const int* __restrict__ rowptr,
                                                const int* __restrict__ elist,
                                                float* __restrict__ agg){
  int n = blockIdx.x;
  int beg = rowptr[n], end = rowptr[n+1];
  int j = threadIdx.x;
  float acc = 0.f;
  if (j < H)
    for (int k = beg; k < end; ++k){
      int s = elist[k];
      acc += m[(size_t)s*H + j];
    }
  if (j < H) agg[(size_t)n*H + j] = acc;
}

// ---------------- pooling: one block per graph (batch sorted -> contiguous rows) ----
// Fuses bn2+relu, mean (pre-divided) and max. No atomics, no memsets.
__global__ __launch_bounds__(256) void pool_g(
    const float* __restrict__ h, const int* __restrict__ batch,
    const float* __restrict__ g2, const float* __restrict__ b2,
    const float* __restrict__ m2, const float* __restrict__ v2,
    float* __restrict__ gmean, float* __restrict__ gmax)
{
  int g = blockIdx.x;
  int lo = 0, hi = NN;
  while (lo < hi){ int mid = (lo+hi)>>1; if (batch[mid] < g) lo = mid+1; else hi = mid; }
  int lo2 = lo, hi2 = NN;
  while (lo2 < hi2){ int mid = (lo2+hi2)>>1; if (batch[mid] < g+1) lo2 = mid+1; else hi2 = mid; }
  int j = threadIdx.x;
  if (j >= H) return;
  float s = g2[j] * rsqrtf(v2[j] + EPSV);
  float mm = m2[j], bb = b2[j];
  float sum = 0.f, mx = 0.f;
  for (int n = lo; n < hi2; ++n){
    float val = fmaxf((h[(size_t)n*H + j] - mm)*s + bb, 0.f);
    sum += val;
    mx = fmaxf(mx, val);
  }
  int c = hi2 - lo;
  gmean[g*H + j] = (c > 0) ? sum/(float)c : 0.f;
  gmax [g*H + j] = mx;   // relu vals >= 0; c==0 leaves 0 (matches ref where())
}

// ---------------- fc1 + bnf + relu ----------------
__global__ __launch_bounds__(256) void fc1_k(
    const float* __restrict__ gmean, const float* __restrict__ gmax,
    const float* __restrict__ W,
    const float* __restrict__ bias,
    const float* __restrict__ fg, const float* __restrict__ fb,
    const float* __restrict__ fm, const float* __restrict__ fv,
    float* __restrict__ out)
{
  int tid = blockIdx.x*256 + threadIdx.x;
  if (tid >= NG*H) return;
  int g = tid / H, j = tid - g*H;
  const float* wr = W + j*2*H;
  float acc = bias[j];
  for (int k = 0; k < H; ++k) acc += gmean[g*H + k] * wr[k];
  for (int k = 0; k < H; ++k) acc += gmax[g*H + k] * wr[H + k];
  float s = fg[j] * rsqrtf(fv[j] + EPSV);
  acc = (acc - fm[j]) * s + fb[j];
  out[tid] = fmaxf(acc, 0.f);
}

__global__ void fc2_k(const float* __restrict__ in, const float* __restrict__ W,
                      const float* __restrict__ bias, float* __restrict__ out)
{
  int tid = blockIdx.x*256 + threadIdx.x;
  if (tid >= NG*2) return;
  int g = tid >> 1, c = tid & 1;
  float acc = bias[c];
  const float* wr = W + c*H;
  const float* xr = in + g*H;
  for (int k = 0; k < H; ++k) acc += xr[k]*wr[k];
  out[tid] = acc;
}

extern "C" void kernel_launch(void* const* d_in, const int* in_sizes, int n_in,
                              void* d_out, int out_size, void* d_ws, size_t ws_size,
                              hipStream_t stream)
{
  const float* x     = (const float*)d_in[0];
  const int*   eidx  = (const int*)d_in[1];
  const int*   batch = (const int*)d_in[2];
  const float* projW = (const float*)d_in[3];
  const float* projb = (const float*)d_in[4];
  const float* bn1g  = (const float*)d_in[5];
  const float* bn1b  = (const float*)d_in[6];
  const float* bn1m  = (const float*)d_in[7];
  const float* bn1v  = (const float*)d_in[8];
  const float* bn2g  = (const float*)d_in[9];
  const float* bn2b  = (const float*)d_in[10];
  const float* bn2m  = (const float*)d_in[11];
  const float* bn2v  = (const float*)d_in[12];
  const float* bnfg  = (const float*)d_in[13];
  const float* bnfb  = (const float*)d_in[14];
  const float* bnfm  = (const float*)d_in[15];
  const float* bnfv  = (const float*)d_in[16];
  const float* ggcW  = (const float*)d_in[17];
  const float* wih   = (const float*)d_in[18];
  const float* whh   = (const float*)d_in[19];
  const float* bih   = (const float*)d_in[20];
  const float* bhh   = (const float*)d_in[21];
  const float* fc1W  = (const float*)d_in[22];
  const float* fc1b  = (const float*)d_in[23];
  const float* fc2W  = (const float*)d_in[24];
  const float* fc2b  = (const float*)d_in[25];

  char* wsp = (char*)d_ws;
  auto alloc = [&](size_t nbytes) {
    char* p = wsp;
    wsp += ((nbytes + 255) / 256) * 256;
    return (void*)p;
  };
  // three rotating fp32 node buffers (bufB oversized for the 208-pitch x copy)
  float* bufA = (float*)alloc((size_t)NN*H*4);
  float* bufB = (float*)alloc((size_t)NN*LPX*4);
  float* bufC = (float*)alloc((size_t)NN*H*4);
  // weights (bf16 split, zero-padded to KP)
  unsigned short* pBh   = (unsigned short*)alloc((size_t)H*KP*2);
  unsigned short* pBl   = (unsigned short*)alloc((size_t)H*KP*2);
  unsigned short* wihBh = (unsigned short*)alloc((size_t)3*H*KP*2);
  unsigned short* wihBl = (unsigned short*)alloc((size_t)3*H*KP*2);
  unsigned short* whhBh = (unsigned short*)alloc((size_t)3*H*KP*2);
  unsigned short* whhBl = (unsigned short*)alloc((size_t)3*H*KP*2);
  unsigned short* gBh[3]; unsigned short* gBl[3];
  for (int i = 0; i < 3; ++i) {
    gBh[i] = (unsigned short*)alloc((size_t)H*KP*2);
    gBl[i] = (unsigned short*)alloc((size_t)H*KP*2);
  }
  float* gmean = (float*)alloc((size_t)NG*H*4);
  float* gmax  = (float*)alloc((size_t)NG*H*4);
  float* fc1o  = (float*)alloc((size_t)NG*H*4);
  const int NB = (NN + SCAN_B - 1) / SCAN_B;
  int* deg    = (int*)alloc((size_t)NN*4);
  int* part   = (int*)alloc((size_t)NN*4);
  int* bsum   = (int*)alloc((size_t)NB*4);
  int* rowptr = (int*)alloc((size_t)(NN+1)*4);
  int* cpos   = (int*)alloc((size_t)NN*4);
  int* elist  = (int*)alloc((size_t)NE*4);

  const int* srcp = eidx;
  const int* dstp = eidx + NE;

  // ---- CSR build (reused all 3 steps) ----
  hipMemsetAsync(deg, 0, (size_t)NN*4, stream);
  hist_k<<<(NE + 255)/256, 256, 0, stream>>>(dstp, deg);
  scan1_k<<<NB, 256, 0, stream>>>(deg, part, bsum, NN);
  scan2_k<<<1, 128, 0, stream>>>(bsum, NB);
  scan3_k<<<(NN + 255)/256, 256, 0, stream>>>(part, bsum, rowptr, cpos, NN);
  fill_k<<<(NE + 255)/256, 256, 0, stream>>>(srcp, dstp, cpos, elist);

  // ---- weight splits (zero-padded K) ----
  cvt_split<<<(int)(((long)H*KP + 255)/256), 256, 0, stream>>>(projW, pBh, pBl, H, D);
  cvt_split<<<(int)(((long)3*H*KP + 255)/256), 256, 0, stream>>>(wih, wihBh, wihBl, 3*H, H);
  cvt_split<<<(int)(((long)3*H*KP + 255)/256), 256, 0, stream>>>(whh, whhBh, whhBl, 3*H, H);
  for (int i = 0; i < 3; ++i)
    cvt_tsplit<<<(H*KP + 255)/256, 256, 0, stream>>>(ggcW + (size_t)i*H*H, gBh[i], gBl[i], H, H);

  // ---- x -> padded pitch-208 copy in bufB ----
  padx_k<<<(int)(((long)NN*LPX + 255)/256), 256, 0, stream>>>(x, bufB);

  // XCD-grouped grids
  const int NPAN = (NN + 127)/128;            // 782
  const int PL8  = (NPAN + 7)/8;              // 98
  const int NJ_G = (H + 127)/128;             // 2 (gemm j-tiles)
  const int NJ_U = (H + 31)/32;               // 7 (gru j-tiles)
  const int GRID_G = 8 * NJ_G * PL8;          // 1568
  const int GRID_U = 8 * NJ_U * PL8;          // 5488

  // proj + bn1 + relu : bufB(x) -> bufA(h)
  mgemm<1><<<GRID_G, 256, 0, stream>>>(bufB, LPX, pBh, pBl, NN, H, NJ_G, NPAN,
                                       projb, bn1g, bn1b, bn1m, bn1v, bufA);

  float* h   = bufA;
  float* m   = bufB;
  float* agg = bufC;
  for (int i = 0; i < 3; ++i) {
    mgemm<0><<<GRID_G, 256, 0, stream>>>(h, H, gBh[i], gBl[i], NN, H, NJ_G, NPAN,
                                         nullptr, nullptr, nullptr, nullptr, nullptr, m);
    gather_k<<<NN, 256, 0, stream>>>(m, rowptr, elist, agg);
    gru6<<<GRID_U, 256, 0, stream>>>(agg, h, wihBh, wihBl, whhBh, whhBl,
                                     bih, bhh, NJ_U, NPAN, m);
    float* t = h; h = m; m = t;   // gru wrote new h into old m
  }

  pool_g<<<NG, 256, 0, stream>>>(h, batch, bn2g, bn2b, bn2m, bn2v, gmean, gmax);
  fc1_k<<<(NG*H + 255)/256, 256, 0, stream>>>(gmean, gmax, fc1W, fc1b,
                                              bnfg, bnfb, bnfm, bnfv, fc1o);
  fc2_k<<<(NG*2 + 255)/256, 256, 0, stream>>>(fc1o, fc2W, fc2b, (float*)d_out);
}